// Round 11
// baseline (1665.871 us; speedup 1.0000x reference)
//
#include <hip/hip_runtime.h>
#include <hip/hip_bf16.h>

// Problem constants (fixed by reference)
#define NSEQ 8192
#define DDIM 512
#define HEADS 8
#define DH 64
#define MLM 256
#define LSUB 32          // NSEQ / MLM
#define WP 256
#define KCONV 33
#define INNER 512        // HEADS*DH
#define QKV_LD 1536

// ---------------- workspace layout (float offsets) ----------------
static const size_t OFF_QKVBF  = 0;          // bf16 8192*1536 = 6,291,456 fl
static const size_t OFF_VT     = 6291456;    // bf16 8*64*8192 = 2,097,152 fl
static const size_t OFF_SC     = 8388608;    // bf16 exp-scores 8*256*8192 (ends 16,777,216)
// pinv overlays inside SC (alive only after scores consumed):
#define PS (8388608)
static const size_t A2R_H = PS + 0;        // each square buf: 262,144 fl (8*256*256 bf16)
static const size_t Z0R_H = PS + 524288;
static const size_t Z0T_H = PS + 1048576;
static const size_t Z1R_H = PS + 1572864;
static const size_t Z1T_H = PS + 2097152;
static const size_t PR_H  = PS + 2621440;
static const size_t PT_H  = PS + 3145728;
static const size_t T1T_H = PS + 3670016;
static const size_t T2T_H = PS + 4194304;
static const size_t A3VT_H= PS + 4718592;  // 65,536 fl
static const size_t A2F32 = PS + 4849664;  // fp32 8*256*256 = 524,288 fl
// after SC:
static const size_t OFF_ATTNBF = 16777216;   // bf16 8192*512 = 2,097,152 fl
static const size_t OFF_PART   = 18874368;   // fp32 pv3 partials 16*8*256*64 = 2,097,152 fl
// enc overlays dead qkv_bf region:
static const size_t OFF_ENC    = 0;          // fp32 8192*512 = 4,194,304 fl
static const size_t OFF_ENCBF  = 4194304;    // bf16 8192*512 = 2,097,152 fl
static const size_t OFF_QKE    = 6291456;    // bf16 8192*512 (vT dead)
// tail region:
static const size_t OFF_DENSEBF= 20971520;   // bf16 8192*512
static const size_t OFF_WQKVBF = 23068672;   // bf16 1536*512
static const size_t OFF_WOUTBF = 23461888;   // bf16 512*512
static const size_t OFF_WQKT   = 23592960;   // bf16 512*512 (wq^T | wk^T)
static const size_t OFF_WVBF   = 23724032;   // bf16 512*512
static const size_t OFF_QL     = 23855104;   // fp32 8*256*64
static const size_t OFF_KL     = 23986176;   // fp32 8*256*64
static const size_t OFF_QLBF   = 24117248;   // bf16 8*256*64
static const size_t OFF_KLSBF  = 24182784;   // bf16 8*256*64 (k_l * 0.125)
static const size_t OFF_BBT    = 24248320;   // bf16 8*64*256
static const size_t OFF_SCAL   = 24313856;   // 2 uints
static const size_t OFF_ALPHA  = 24313872;   // 8192 fp32
static const size_t OFF_DEN3   = 24322064;   // 2048 fp32

__device__ __forceinline__ float bf2f(unsigned short u) {
    return __uint_as_float(((unsigned int)u) << 16);
}
__device__ __forceinline__ unsigned short f2bf(float x) {
    unsigned int u = __float_as_uint(x);
    u += 0x7FFFu + ((u >> 16) & 1u);   // RNE
    return (unsigned short)(u >> 16);
}

typedef __attribute__((ext_vector_type(8))) short bf16x8;
typedef __attribute__((ext_vector_type(4))) float f32x4;

__device__ __forceinline__ void gload_lds16(const void* g, void* l) {
    __builtin_amdgcn_global_load_lds(
        (const __attribute__((address_space(1))) unsigned int*)g,
        (__attribute__((address_space(3))) unsigned int*)l, 16, 0, 0);
}

// ---------------- fp32 -> bf16 conversion (8 elems/thread) ----------------
__global__ __launch_bounds__(256) void cvt_bf16_k(
    const float* __restrict__ in, unsigned short* __restrict__ out)
{
    size_t i = ((size_t)blockIdx.x * 256 + threadIdx.x) * 8;
    float4 a = *reinterpret_cast<const float4*>(in + i);
    float4 b = *reinterpret_cast<const float4*>(in + i + 4);
    uint4 p;
    p.x = (unsigned int)f2bf(a.x) | ((unsigned int)f2bf(a.y) << 16);
    p.y = (unsigned int)f2bf(a.z) | ((unsigned int)f2bf(a.w) << 16);
    p.z = (unsigned int)f2bf(b.x) | ((unsigned int)f2bf(b.y) << 16);
    p.w = (unsigned int)f2bf(b.z) | ((unsigned int)f2bf(b.w) << 16);
    *reinterpret_cast<uint4*>(out + i) = p;
}

// ---------------- transpose + convert: out[c][r] = bf16(in[r][c]) ----------
__global__ __launch_bounds__(256) void tcvt_bf16_k(
    const float* __restrict__ in, unsigned short* __restrict__ out, int R, int C)
{
    int idx = blockIdx.x * 256 + threadIdx.x;
    if (idx < R * C) {
        int oc = idx / R;
        int orow = idx % R;
        out[idx] = f2bf(in[(size_t)orow * C + oc]);
    }
}

// ===== batched bf16 MFMA NT GEMM, 64x128 tile, BK=64 =====
// C[b,m,n] = sum_k A[b,m,k]*B[b,n,k]; 4 waves (2x2), wave = 32x64.
// epi: 0 none, 1 exp, 2 gated-final-blend, 3 exp + den row-sum atomic
__global__ __launch_bounds__(256) void gemm_mfma_ntb(
    const unsigned short* __restrict__ A, int lda, size_t sA,
    const unsigned short* __restrict__ B, int ldb, size_t sB,
    float* __restrict__ C, unsigned short* __restrict__ Cbf, int ldc, size_t sC,
    int K, const float* __restrict__ bias, const float* __restrict__ addsrc,
    const float* __restrict__ alphav, float* __restrict__ denv, int epi)
{
    __shared__ __align__(16) unsigned short As[64 * 64];
    __shared__ __align__(16) unsigned short Bs[128 * 64];
    const int tid = threadIdx.x;
    const int wave = tid >> 6, lane = tid & 63;
    const int l15 = lane & 15, l4 = lane >> 4;
    const int wm = wave >> 1, wn = wave & 1;
    const size_t bm = (size_t)blockIdx.x * 64;
    const size_t bn = (size_t)blockIdx.y * 128;
    const int z = blockIdx.z;
    const unsigned short* Ab = A + (size_t)z * sA;
    const unsigned short* Bb = B + (size_t)z * sB;
    const int swzr = (l15 & 7) << 3;
    f32x4 acc[2][4] = {};
    for (int k0 = 0; k0 < K; k0 += 64) {
        __syncthreads();
#pragma unroll
        for (int c2 = 0; c2 < 2; ++c2) {       // A: 64x64 = 512 x 16B
            int id = c2 * 256 + tid;
            int row = id >> 3;
            int cg = ((id & 7) ^ (row & 7)) << 3;
            gload_lds16(Ab + (bm + row) * (size_t)lda + k0 + cg, As + id * 8);
        }
#pragma unroll
        for (int c2 = 0; c2 < 4; ++c2) {       // B: 128x64 = 1024 x 16B
            int id = c2 * 256 + tid;
            int row = id >> 3;
            int cg = ((id & 7) ^ (row & 7)) << 3;
            gload_lds16(Bb + (bn + row) * (size_t)ldb + k0 + cg, Bs + id * 8);
        }
        __syncthreads();
#pragma unroll
        for (int c = 0; c < 2; ++c) {
            bf16x8 af[2], bfv[4];
#pragma unroll
            for (int i = 0; i < 2; ++i)
                af[i] = *reinterpret_cast<const bf16x8*>(
                    &As[(wm * 32 + i * 16 + l15) * 64 + ((c * 32 + l4 * 8) ^ swzr)]);
#pragma unroll
            for (int j = 0; j < 4; ++j)
                bfv[j] = *reinterpret_cast<const bf16x8*>(
                    &Bs[(wn * 64 + j * 16 + l15) * 64 + ((c * 32 + l4 * 8) ^ swzr)]);
#pragma unroll
            for (int i = 0; i < 2; ++i)
#pragma unroll
                for (int j = 0; j < 4; ++j)
                    acc[i][j] = __builtin_amdgcn_mfma_f32_16x16x32_bf16(
                        af[i], bfv[j], acc[i][j], 0, 0, 0);
        }
    }
    float* Cz = C ? C + (size_t)z * sC : nullptr;
    unsigned short* Cbz = Cbf ? Cbf + (size_t)z * sC : nullptr;
    if (epi == 3) {
        // exp + bf16 store + per-row denominator accumulation
#pragma unroll
        for (int i = 0; i < 2; ++i)
#pragma unroll
            for (int r = 0; r < 4; ++r) {
                size_t row = bm + wm * 32 + i * 16 + l4 * 4 + r;
                float s = 0.f;
#pragma unroll
                for (int j = 0; j < 4; ++j) {
                    size_t col = bn + wn * 64 + j * 16 + l15;
                    float e = __expf(acc[i][j][r]);
                    s += e;
                    Cbz[row * (size_t)ldc + col] = f2bf(e);
                }
                s += __shfl_xor(s, 1); s += __shfl_xor(s, 2);
                s += __shfl_xor(s, 4); s += __shfl_xor(s, 8);
                if (l15 == 0) atomicAdd(denv + (size_t)z * MLM + row, s);
            }
        return;
    }
#pragma unroll
    for (int i = 0; i < 2; ++i)
#pragma unroll
        for (int j = 0; j < 4; ++j)
#pragma unroll
            for (int r = 0; r < 4; ++r) {
                size_t row = bm + wm * 32 + i * 16 + l4 * 4 + r;
                size_t col = bn + wn * 64 + j * 16 + l15;
                float v = acc[i][j][r];
                if (bias) v += bias[col];
                if (epi == 2) {
                    float xl = alphav[row] * v;
                    float w = 1.f / (1.f + __expf(xl));
                    float sq = w * w;
                    v = xl * 2.f * sq + 2.f * addsrc[row * (size_t)ldc + col] * (1.f - sq);
                    Cz[row * (size_t)ldc + col] = v;
                } else {
                    if (addsrc) v += addsrc[row * (size_t)ldc + col];
                    if (epi == 1) v = __expf(v);
                    if (Cz)  Cz[row * (size_t)ldc + col] = v;
                    if (Cbz) Cbz[row * (size_t)ldc + col] = f2bf(v);
                }
            }
}

// ===== fused pinv: one block per head, all 25 GEMM stages in-kernel =====
// 1024 threads = 16 waves in a 4x4 grid of 64x64 tiles over the 256x256 output.
// Operand fragments read straight from L2 (per-head working set ~0.8 MB).
__device__ __forceinline__ void pinv_stage(
    const unsigned short* __restrict__ A,   // [M x 256] row-major
    const unsigned short* __restrict__ Bt,  // [N x 256] row-major (B transposed)
    unsigned short* __restrict__ Cr,        // [M x 256] row-major (optional)
    unsigned short* __restrict__ Ct,        // [256 x M] (optional)
    float alpha, float beta,
    int wm, int wn, int l15, int l4)
{
    f32x4 acc[4][4] = {};
    for (int k0 = 0; k0 < 256; k0 += 32) {
        bf16x8 af[4], bf[4];
#pragma unroll
        for (int i = 0; i < 4; ++i)
            af[i] = *reinterpret_cast<const bf16x8*>(
                &A[(size_t)(wm * 64 + i * 16 + l15) * 256 + k0 + l4 * 8]);
#pragma unroll
        for (int j = 0; j < 4; ++j)
            bf[j] = *reinterpret_cast<const bf16x8*>(
                &Bt[(size_t)(wn * 64 + j * 16 + l15) * 256 + k0 + l4 * 8]);
#pragma unroll
        for (int i = 0; i < 4; ++i)
#pragma unroll
            for (int j = 0; j < 4; ++j)
                acc[i][j] = __builtin_amdgcn_mfma_f32_16x16x32_bf16(
                    af[i], bf[j], acc[i][j], 0, 0, 0);
    }
#pragma unroll
    for (int i = 0; i < 4; ++i)
#pragma unroll
        for (int j = 0; j < 4; ++j) {
            int row0 = wm * 64 + i * 16 + l4 * 4;
            int col = wn * 64 + j * 16 + l15;
            unsigned short hv[4];
#pragma unroll
            for (int r = 0; r < 4; ++r) {
                float v = beta * acc[i][j][r];
                if (alpha != 0.f)
                    v += alpha * bf2f(A[(size_t)(row0 + r) * 256 + col]);
                hv[r] = f2bf(v);
                if (Cr) Cr[(size_t)(row0 + r) * 256 + col] = hv[r];
            }
            if (Ct)
                *reinterpret_cast<ushort4*>(&Ct[(size_t)col * 256 + row0]) =
                    make_ushort4(hv[0], hv[1], hv[2], hv[3]);
        }
}

__global__ __launch_bounds__(1024) void pinv_fused_k(
    const unsigned short* __restrict__ a2r,
    unsigned short* __restrict__ z0r, unsigned short* __restrict__ z0t,
    unsigned short* __restrict__ z1r, unsigned short* __restrict__ z1t,
    unsigned short* __restrict__ pr,  unsigned short* __restrict__ pt,
    unsigned short* __restrict__ t1t, unsigned short* __restrict__ t2t,
    const unsigned short* __restrict__ a3vt,
    unsigned short* __restrict__ bbT)
{
    const size_t off = (size_t)blockIdx.x * 65536;
    const int tid = threadIdx.x;
    const int lane = tid & 63, wave = tid >> 6;
    const int l15 = lane & 15, l4 = lane >> 4;
    const int wm = wave >> 2, wn = wave & 3;
#define PFENCE() do { __threadfence(); __syncthreads(); } while (0)
#pragma unroll 1
    for (int it = 0; it < 6; ++it) {
        const unsigned short* zr = ((it & 1) ? z1r : z0r) + off;
        const unsigned short* zt = ((it & 1) ? z1t : z0t) + off;
        unsigned short* orr = ((it & 1) ? z0r : z1r) + off;
        unsigned short* ot  = ((it & 1) ? z0t : z1t) + off;
        // P = a2 @ z
        pinv_stage(a2r + off, zt, pr + off, pt + off, 0.f, 1.f, wm, wn, l15, l4);
        PFENCE();
        // T1 = 7P - P@P
        pinv_stage(pr + off, pt + off, nullptr, t1t + off, 7.f, -1.f, wm, wn, l15, l4);
        PFENCE();
        // T2 = 15P - P@T1
        pinv_stage(pr + off, t1t + off, nullptr, t2t + off, 15.f, -1.f, wm, wn, l15, l4);
        PFENCE();
        // z' = 3.25 z - 0.25 z@T2
        pinv_stage(zr, t2t + off, orr, ot, 3.25f, -0.25f, wm, wn, l15, l4);
        PFENCE();
    }
    // bbT[d,n] = sum_k a3vT[d,k] * z[n,k]   (final z row-major is in z0r)
    if (wm == 0)
        pinv_stage(a3vt + (size_t)blockIdx.x * 16384, z0r + off,
                   bbT + (size_t)blockIdx.x * 16384, nullptr, 0.f, 1.f,
                   0, wn, l15, l4);
#undef PFENCE
}

// ===== pv3: partials[kc][h][i][d] = sum_{j in chunk} P[h,i,j]*vT[h,d,j] =====
__global__ __launch_bounds__(256) void pv3_mfma(
    const unsigned short* __restrict__ sc, const unsigned short* __restrict__ vT,
    float* __restrict__ part)
{
    __shared__ __align__(16) unsigned short As[64 * 64];
    __shared__ __align__(16) unsigned short Bs[64 * 64];
    const int tid = threadIdx.x;
    const int wave = tid >> 6, lane = tid & 63;
    const int l15 = lane & 15, l4 = lane >> 4;
    const int wm = wave >> 1, wn = wave & 1;
    const int it = blockIdx.x, kc = blockIdx.y, h = blockIdx.z;
    const unsigned short* Ap = sc + (size_t)h * MLM * NSEQ + (size_t)(it * 64) * NSEQ + kc * 512;
    const unsigned short* Bp = vT + (size_t)h * DH * NSEQ + kc * 512;
    const int swzr = (l15 & 7) << 3;
    f32x4 acc[2][2] = {};
    for (int k0 = 0; k0 < 512; k0 += 64) {
        __syncthreads();
#pragma unroll
        for (int c2 = 0; c2 < 2; ++c2) {
            int id = c2 * 256 + tid;
            int row = id >> 3;
            int cg = ((id & 7) ^ (row & 7)) << 3;
            gload_lds16(Ap + (size_t)row * NSEQ + k0 + cg, As + id * 8);
        }
#pragma unroll
        for (int c2 = 0; c2 < 2; ++c2) {
            int id = c2 * 256 + tid;
            int row = id >> 3;
            int cg = ((id & 7) ^ (row & 7)) << 3;
            gload_lds16(Bp + (size_t)row * NSEQ + k0 + cg, Bs + id * 8);
        }
        __syncthreads();
#pragma unroll
        for (int ks = 0; ks < 2; ++ks) {
            bf16x8 af[2], bfv[2];
#pragma unroll
            for (int i = 0; i < 2; ++i)
                af[i] = *reinterpret_cast<const bf16x8*>(
                    &As[(wm * 32 + i * 16 + l15) * 64 + ((ks * 32 + l4 * 8) ^ swzr)]);
#pragma unroll
            for (int j = 0; j < 2; ++j)
                bfv[j] = *reinterpret_cast<const bf16x8*>(
                    &Bs[(wn * 32 + j * 16 + l15) * 64 + ((ks * 32 + l4 * 8) ^ swzr)]);
#pragma unroll
            for (int i = 0; i < 2; ++i)
#pragma unroll
                for (int j = 0; j < 2; ++j)
                    acc[i][j] = __builtin_amdgcn_mfma_f32_16x16x32_bf16(af[i], bfv[j], acc[i][j], 0, 0, 0);
        }
    }
    float* Cp = part + ((size_t)(kc * 8 + h) * MLM + it * 64) * DH;
#pragma unroll
    for (int i = 0; i < 2; ++i)
#pragma unroll
        for (int j = 0; j < 2; ++j)
#pragma unroll
            for (int r = 0; r < 4; ++r)
                Cp[(wm * 32 + i * 16 + l4 * 4 + r) * DH + wn * 32 + j * 16 + l15] = acc[i][j][r];
}

// ===== fused a1: QK + exp-softmax + PV + depthwise conv, writes bf16 attn =====
// LDS: A(8KB) overlapped by P(32KB) overlapped by att(16KB)+vbuf(12KB); kls read from L2.
__global__ __launch_bounds__(256) void a1_fused(
    const unsigned short* __restrict__ qkvbf,
    const unsigned short* __restrict__ kls,     // [h][256][64] (k_l * 0.125)
    const unsigned short* __restrict__ bbT,     // [h][64][256]
    const float* __restrict__ kern,
    unsigned short* __restrict__ attnbf)
{
    __shared__ __align__(16) unsigned short lds[16384];  // 32 KB
    __shared__ float den[2][64];
    __shared__ float kc_s[KCONV];
    const int tid = threadIdx.x;
    const int wave = tid >> 6, lane = tid & 63;
    const int l15 = lane & 15, l4 = lane >> 4;
    const int wm = wave >> 1, wn = wave & 1;
    const int n0 = blockIdx.x * 64;
    const int h = blockIdx.y;
    const int swzr = (l15 & 7) << 3;

    if (tid < KCONV) kc_s[tid] = kern[h * KCONV + tid];
    // stage A (q rows 64x64) only; kls fragments come straight from L2
#pragma unroll
    for (int c2 = 0; c2 < 2; ++c2) {
        int id = c2 * 256 + tid;
        int row = id >> 3, cg = ((id & 7) ^ (row & 7)) << 3;
        gload_lds16(qkvbf + (size_t)(n0 + row) * QKV_LD + h * DH + cg, lds + id * 8);
    }
    __syncthreads();
    // QK: S = q . kls^T  (64 x 256), wave tile 32 x 128
    const unsigned short* klsh = kls + (size_t)h * (MLM * DH);
    f32x4 acc[2][8] = {};
#pragma unroll
    for (int c = 0; c < 2; ++c) {
        bf16x8 af[2], bv[8];
#pragma unroll
        for (int i = 0; i < 2; ++i) {
            int row = wm * 32 + i * 16 + l15;
            af[i] = *reinterpret_cast<const bf16x8*>(&lds[row * 64 + ((c * 32 + l4 * 8) ^ swzr)]);
        }
#pragma unroll
        for (int j = 0; j < 8; ++j) {
            int brow = wn * 128 + j * 16 + l15;
            bv[j] = *reinterpret_cast<const bf16x8*>(&klsh[brow * 64 + c * 32 + l4 * 8]);
        }
#pragma unroll
        for (int i = 0; i < 2; ++i)
#pragma unroll
            for (int j = 0; j < 8; ++j)
                acc[i][j] = __builtin_amdgcn_mfma_f32_16x16x32_bf16(af[i], bv[j], acc[i][j], 0, 0, 0);
    }
    __syncthreads();   // all A reads complete -> P may overlay
    // exp (scores tiny: no max), row sums, write P bf16 swizzled at lds[0]
    float rs[2][4] = {};
#pragma unroll
    for (int i = 0; i < 2; ++i)
#pragma unroll
        for (int j = 0; j < 8; ++j)
#pragma unroll
            for (int r = 0; r < 4; ++r) {
                float e = __expf(acc[i][j][r]);
                rs[i][r] += e;
                int row = wm * 32 + i * 16 + l4 * 4 + r;
                int col = wn * 128 + j * 16 + l15;
                lds[row * 256 + (col ^ ((row & 7) << 3))] = f2bf(e);
            }
#pragma unroll
    for (int i = 0; i < 2; ++i)
#pragma unroll
        for (int r = 0; r < 4; ++r) {
            float s = rs[i][r];
            s += __shfl_xor(s, 1); s += __shfl_xor(s, 2);
            s += __shfl_xor(s, 4); s += __shfl_xor(s, 8);
            if (l15 == 0) den[wn][wm * 32 + i * 16 + l4 * 4 + r] = s;
        }
    __syncthreads();
    // PV: out = P @ bb  (64 x 64), wave tile 32 x 32; B frags from L2
    f32x4 acc2[2][2] = {};
    const unsigned short* bbh = bbT + (size_t)h * DH * MLM;
#pragma unroll
    for (int k0 = 0; k0 < 256; k0 += 32) {
        bf16x8 af2[2], bv2[2];
#pragma unroll
        for (int i = 0; i < 2; ++i) {
            int row = wm * 32 + i * 16 + l15;
            af2[i] = *reinterpret_cast<const bf16x8*>(
                &lds[row * 256 + ((k0 + l4 * 8) ^ ((row & 7) << 3))]);
        }
#pragma unroll
        for (int j = 0; j < 2; ++j) {
            int d = wn * 32 + j * 16 + l15;
            bv2[j] = *reinterpret_cast<const bf16x8*>(&bbh[d * MLM + k0 + l4 * 8]);
        }
#pragma unroll
        for (int i = 0; i < 2; ++i)
#pragma unroll
            for (int j = 0; j < 2; ++j)
                acc2[i][j] = __builtin_amdgcn_mfma_f32_16x16x32_bf16(af2[i], bv2[j], acc2[i][j], 0, 0, 0);
    }
    __syncthreads();   // P reads done; reuse LDS
    // normalized PV -> LDS fp32 att[64][64] at lds[0]; v window 96x64 at lds[8192]
    float* att = reinterpret_cast<float*>(lds);              // 16 KB
    unsigned short* vbuf = &lds[8192];                       // 12 KB
#pragma unroll
    for (int i = 0; i < 2; ++i)
#pragma unroll
        for (int r = 0; r < 4; ++r) {
            int row = wm * 32 + i * 16 + l4 * 4 + r;
            float inv = 1.f / (den[0][row] + den[1][row]);
#pragma unroll
            for (int j = 0; j < 2; ++j)
                att[row * 64 + wn * 32 + j * 16 + l15] = acc2[i][j][r] * inv;
        }
#pragma unroll
    for (int s = 0; s < 6; ++s) {
        int id = s * 256 + tid;
        int r = id >> 4, c4 = (id & 15) * 4;
        int n = n0 - 16 + r;
        ushort4 u = {0, 0, 0, 0};
        if (n >= 0 && n < NSEQ)
            u = *reinterpret_cast<const ushort4*>(qkvbf + (size_t)n * QKV_LD + 1024 + h * 64 + c4);
        *reinterpret_cast<ushort4*>(vbuf + r * 64 + c4) = u;
    }
    __syncthreads();
    // conv: each thread owns 16 rows of one column
    const int col = tid & 63, rowg = tid >> 6;
    float vwin[48];
#pragma unroll
    for (int t = 0; t < 48; ++t) vwin[t] = bf2f(vbuf[(rowg * 16 + t) * 64 + col]);
#pragma unroll
    for (int rr = 0; rr < 16; ++rr) {
        float cv = 0.f;
#pragma unroll
        for (int t = 0; t < KCONV; ++t) cv += kc_s[t] * vwin[rr + t];
        int row = rowg * 16 + rr;
        attnbf[(size_t)(n0 + row) * INNER + h * DH + col] = f2bf(att[row * 64 + col] + cv);
    }
}

// ------------- landmark means from bf16 qkv (+ bf16 copies) -------------
__global__ __launch_bounds__(64) void landmark2_k(
    const unsigned short* __restrict__ qkvbf, float* __restrict__ q_l, float* __restrict__ k_l,
    unsigned short* __restrict__ ql_bf, unsigned short* __restrict__ kls_bf)
{
    int m = blockIdx.x, h = blockIdx.y, d = threadIdx.x;
    float sq = 0.f, sk = 0.f;
    for (int i = 0; i < LSUB; ++i) {
        size_t n = (size_t)m * LSUB + i;
        sq += bf2f(qkvbf[n * QKV_LD + h * DH + d]);
        sk += bf2f(qkvbf[n * QKV_LD + 512 + h * DH + d]);
    }
    float qv = sq * (0.125f / (float)LSUB);
    float kv = sk * (1.f / (float)LSUB);
    size_t o = ((size_t)h * MLM + m) * DH + d;
    q_l[o] = qv; k_l[o] = kv;
    ql_bf[o] = f2bf(qv);
    kls_bf[o] = f2bf(kv * 0.125f);
}

// ------------- v transpose: vT[h][d][n] = qkv_bf[n][1024+h*64+d] -------------
__global__ __launch_bounds__(256) void vt_k(
    const unsigned short* __restrict__ qkvbf, unsigned short* __restrict__ vT)
{
    __shared__ unsigned short tile[128][72];
    const int t = threadIdx.x;
    const int n0 = blockIdx.x * 128;
    const int h = blockIdx.y;
#pragma unroll
    for (int s = 0; s < 4; ++s) {
        int cid = s * 256 + t;
        int row = cid >> 3, ch = (cid & 7) * 8;
        uint4 v = *reinterpret_cast<const uint4*>(
            qkvbf + (size_t)(n0 + row) * QKV_LD + 1024 + h * 64 + ch);
        *reinterpret_cast<uint4*>(&tile[row][ch]) = v;
    }
    __syncthreads();
#pragma unroll
    for (int s = 0; s < 4; ++s) {
        int cid = s * 256 + t;
        int d = cid >> 4, nch = (cid & 15) * 8;
        unsigned short o[8];
#pragma unroll
        for (int i = 0; i < 8; ++i) o[i] = tile[nch + i][d];
        *reinterpret_cast<uint4*>(vT + (size_t)h * DH * NSEQ + (size_t)d * NSEQ + n0 + nch) =
            *reinterpret_cast<uint4*>(o);
    }
}

// ------------- a2 = softmax(q_l @ k_l^T) rows -------------
__global__ __launch_bounds__(256) void a2_k(
    const float* __restrict__ q_l, const float* __restrict__ k_l, float* __restrict__ a2)
{
    int i = blockIdx.x, h = blockIdx.y, t = threadIdx.x;
    __shared__ float ql[64];
    __shared__ float red[256];
    if (t < 64) ql[t] = q_l[((size_t)h * MLM + i) * DH + t];
    __syncthreads();
    const float* kr = k_l + ((size_t)h * MLM + t) * DH;
    float s = 0.f;
#pragma unroll
    for (int d = 0; d < 64; d += 4) {
        float4 kv = *reinterpret_cast<const float4*>(kr + d);
        s += kv.x * ql[d] + kv.y * ql[d + 1] + kv.z * ql[d + 2] + kv.w * ql[d + 3];
    }
    red[t] = s; __syncthreads();
    for (int off = 128; off > 0; off >>= 1) { if (t < off) red[t] = fmaxf(red[t], red[t + off]); __syncthreads(); }
    float m = red[0]; __syncthreads();
    float e = __expf(s - m);
    red[t] = e; __syncthreads();
    for (int off = 128; off > 0; off >>= 1) { if (t < off) red[t] += red[t + off]; __syncthreads(); }
    a2[(((size_t)h * MLM + i) * MLM) + t] = e / red[0];
}

// ------------- global max of row/col abs-sums of a2 -------------
__global__ __launch_bounds__(256) void absmax_k(
    const float* __restrict__ a2, unsigned int* __restrict__ scal)
{
    int b = blockIdx.x, t = threadIdx.x;
    __shared__ float red[256];
    float sum = 0.f;
    if (b < 8) {
        const float* r = a2 + ((size_t)b * MLM + t) * MLM;
        for (int j = 0; j < MLM; ++j) sum += fabsf(r[j]);
    } else {
        int h = b - 8;
        for (int i = 0; i < MLM; ++i) sum += fabsf(a2[((size_t)h * MLM + i) * MLM + t]);
    }
    red[t] = sum; __syncthreads();
    for (int off = 128; off > 0; off >>= 1) { if (t < off) red[t] = fmaxf(red[t], red[t + off]); __syncthreads(); }
    if (t == 0) atomicMax(scal + (b < 8 ? 0 : 1), __float_as_uint(red[0]));
}

// ------------- zinit2: a2 + z0 (row & T) to bf16 -------------
__global__ __launch_bounds__(256) void zinit2_k(
    const float* __restrict__ a2, const unsigned int* __restrict__ scal,
    unsigned short* __restrict__ a2h,
    unsigned short* __restrict__ zrh, unsigned short* __restrict__ zth)
{
    int idx = blockIdx.x * 256 + threadIdx.x;
    float inv = 1.f / (__uint_as_float(scal[0]) * __uint_as_float(scal[1]));
    int h = idx >> 16, rem = idx & 65535, i = rem >> 8, j = rem & 255;
    float aij = a2[idx];
    a2h[idx] = f2bf(aij);
    zth[idx] = f2bf(aij * inv);                              // z0T[i][j] = a2[i][j]*inv
    zrh[idx] = f2bf(a2[((size_t)h << 16) + (j << 8) + i] * inv);  // z0row[i][j] = a2[j][i]*inv
}

// ------------- red3: sum partials, divide, write a3v^T bf16 -------------
__global__ __launch_bounds__(256) void red3_k(
    const float* __restrict__ part, const float* __restrict__ den3,
    unsigned short* __restrict__ a3vth)
{
    int o = blockIdx.x * 256 + threadIdx.x;   // [8][256][64]
    float s = 0.f;
#pragma unroll
    for (int kc = 0; kc < 16; ++kc) s += part[(size_t)kc * 131072 + o];
    s /= den3[o >> 6];
    int h = o >> 14, i = (o >> 6) & 255, d = o & 63;
    a3vth[(h << 14) + (d << 8) + i] = f2bf(s);
}

// ------------- sparse edge scores: 8 lanes/edge, 32 dims/lane -------------
__global__ __launch_bounds__(256) void edge2_k(
    const unsigned short* __restrict__ qke,
    const int* __restrict__ rows, const int* __restrict__ cols,
    const float* __restrict__ vals, float* __restrict__ A_raw)
{
    const int e = blockIdx.x * 32 + (threadIdx.x >> 3);
    const int g = threadIdx.x & 7;
    const int r = rows[e], c = cols[e];
    const unsigned short* qr = qke + (size_t)r * 512 + g * 32;
    const unsigned short* kr = qke + (size_t)c * 512 + 256 + g * 32;
    float s = 0.f;
#pragma unroll
    for (int u = 0; u < 4; ++u) {
        uint4 qa = *reinterpret_cast<const uint4*>(qr + u * 8);
        uint4 ka = *reinterpret_cast<const uint4*>(kr + u * 8);
        unsigned int qw[4] = {qa.x, qa.y, qa.z, qa.w};
        unsigned int kw[4] = {ka.x, ka.y, ka.z, ka.w};
#pragma unroll
        for (int q = 0; q < 4; ++q) {
            s += bf2f((unsigned short)(qw[q] & 0xFFFF)) * bf2f((unsigned short)(kw[q] & 0xFFFF));
            s += bf2f((unsigned short)(qw[q] >> 16)) * bf2f((unsigned short)(kw[q] >> 16));
        }
    }
    s += __shfl_xor(s, 1); s += __shfl_xor(s, 2); s += __shfl_xor(s, 4);
    if (g == 0) atomicAdd(&A_raw[r], s * vals[e] * 0.0625f);
}

// ------------- alpha = softmax(A_raw) -------------
__global__ __launch_bounds__(1024) void alpha_k(
    const float* __restrict__ A_raw, float* __restrict__ alpha)
{
    __shared__ float red[1024];
    int t = threadIdx.x;
    float m = -1e30f;
    for (int i = t; i < NSEQ; i += 1024) m = fmaxf(m, A_raw[i]);
    red[t] = m; __syncthreads();
    for (int off = 512; off > 0; off >>= 1) { if (t < off) red[t] = fmaxf(red[t], red[t + off]); __syncthreads(); }
    m = red[0]; __syncthreads();
    float s = 0.f;
    for (int i = t; i < NSEQ; i += 1024) s += __expf(A_raw[i] - m);
    red[t] = s; __syncthreads();
    for (int off = 512; off > 0; off >>= 1) { if (t < off) red[t] += red[t + off]; __syncthreads(); }
    float inv = 1.f / red[0];
    for (int i = t; i < NSEQ; i += 1024) alpha[i] = __expf(A_raw[i] - m) * inv;
}

extern "C" void kernel_launch(void* const* d_in, const int* in_sizes, int n_in,
                              void* d_out, int out_size, void* d_ws, size_t ws_size,
                              hipStream_t stream)
{
    const float* dense      = (const float*)d_in[0];
    const int*   adj_rows   = (const int*)d_in[1];
    const int*   adj_cols   = (const int*)d_in[2];
    const float* adj_vals   = (const float*)d_in[3];
    const float* wq         = (const float*)d_in[4];
    const float* wk         = (const float*)d_in[5];
    const float* w_qkv      = (const float*)d_in[6];
    const float* w_out      = (const float*)d_in[7];
    const float* b_out      = (const float*)d_in[8];
    const float* res_kernel = (const float*)d_in[9];
    const float* wv_w       = (const float*)d_in[10];
    const float* wv_b       = (const float*)d_in[11];
    const int E = in_sizes[1];

    float* ws  = (float*)d_ws;
    float* out = (float*)d_out;
    float* A_raw = out + (size_t)NSEQ * DDIM;

    unsigned short* qkv_bf   = (unsigned short*)(ws + OFF_QKVBF);
    unsigned short* vT       = (unsigned short*)(ws + OFF_VT);
    unsigned short* sc       = (unsigned short*)(ws + OFF_SC);
    unsigned short* attn_bf  = (unsigned short*)(ws + OFF_ATTNBF);
    unsigned short* qke_bf   = (unsigned short*)(ws + OFF_QKE);
    unsigned short* dense_bf = (unsigned short*)(ws + OFF_DENSEBF);
    unsigned short* wqkv_bf  = (unsigned short*)(ws + OFF_WQKVBF);
    unsigned short* wout_bf  = (unsigned short*)(ws + OFF_WOUTBF);
    unsigned short* wqkT_bf  = (unsigned short*)(ws + OFF_WQKT);
    unsigned short* wv_bf    = (unsigned short*)(ws + OFF_WVBF);
    unsigned short* ql_bf    = (unsigned short*)(ws + OFF_QLBF);
    unsigned short* kls_bf   = (unsigned short*)(ws + OFF_KLSBF);
    unsigned short* bbT_bf   = (unsigned short*)(ws + OFF_BBT);
    unsigned short* enc_bf   = (unsigned short*)(ws + OFF_ENCBF);

#define U16(off) ((unsigned short*)(ws + (off)))

    (void)hipMemsetAsync(A_raw, 0, NSEQ * sizeof(float), stream);
    (void)hipMemsetAsync(ws + OFF_SCAL, 0, 2 * sizeof(unsigned int), stream);
    (void)hipMemsetAsync(ws + OFF_DEN3, 0, HEADS * MLM * sizeof(float), stream);

    // ---- input conversions ----
    cvt_bf16_k<<<(NSEQ * DDIM) / 2048, 256, 0, stream>>>(dense, dense_bf);
    cvt_bf16_k<<<(1536 * DDIM) / 2048, 256, 0, stream>>>(w_qkv, wqkv_bf);

    // qkv = dense @ w_qkv^T  -> bf16
    gemm_mfma_ntb<<<dim3(NSEQ / 64, 1536 / 128, 1), 256, 0, stream>>>(
        dense_bf, DDIM, 0, wqkv_bf, DDIM, 0, nullptr, qkv_bf, QKV_LD, 0,
        DDIM, nullptr, nullptr, nullptr, nullptr, 0);

    landmark2_k<<<dim3(MLM, HEADS), 64, 0, stream>>>(
        qkv_bf, ws + OFF_QL, ws + OFF_KL, ql_bf, kls_bf);
    vt_k<<<dim3(NSEQ / 128, HEADS), 256, 0, stream>>>(qkv_bf, vT);

    // ---- a3 pipeline (exp-scores + fused den accumulation) ----
    gemm_mfma_ntb<<<dim3(MLM / 64, NSEQ / 128, HEADS), 256, 0, stream>>>(
        ql_bf, DH, (size_t)MLM * DH, qkv_bf + 512, QKV_LD, DH,
        nullptr, sc, NSEQ, (size_t)MLM * NSEQ, DH, nullptr, nullptr, nullptr,
        ws + OFF_DEN3, 3);
    pv3_mfma<<<dim3(4, 16, HEADS), 256, 0, stream>>>(sc, vT, ws + OFF_PART);
    red3_k<<<512, 256, 0, stream>>>(ws + OFF_PART, ws + OFF_DEN3, U16(A3VT_H));

    a2_k<<<dim3(MLM, HEADS), 256, 0, stream>>>(ws + OFF_QL, ws + OFF_KL, ws + A2F32);
    absmax_k<<<16, 256, 0, stream>>>(ws + A2F32, (unsigned int*)(ws + OFF_SCAL));
    zinit2_k<<<(HEADS * MLM * MLM) / 256, 256, 0, stream>>>(
        ws + A2F32, (const unsigned int*)(ws + OFF_SCAL),
        U16(A2R_H), U16(Z0R_H), U16(Z0T_H));

    // ---- fused pinv: all 25 GEMM stages in one launch (1 block/head) ----
    pinv_fused_k<<<HEADS, 1024, 0, stream>>>(
        U16(A2R_H), U16(Z0R_H), U16(Z0T_H), U16(Z1R_H), U16(Z1T_H),
        U16(PR_H), U16(PT_H), U16(T1T_H), U16(T2T_H),
        U16(A3VT_H), bbT_bf);

    // ---- fused a1 (QK + exp-softmax + PV + conv -> bf16 attn) ----
    a1_fused<<<dim3(NSEQ / 64, HEADS), 256, 0, stream>>>(
        qkv_bf, kls_bf, bbT_bf, res_kernel, attn_bf);

    // ---- late weights to bf16 ----
    cvt_bf16_k<<<(DDIM * INNER) / 2048, 256, 0, stream>>>(w_out, wout_bf);
    tcvt_bf16_k<<<(WP * DDIM + 255) / 256, 256, 0, stream>>>(wq, wqkT_bf, DDIM, WP);
    tcvt_bf16_k<<<(WP * DDIM + 255) / 256, 256, 0, stream>>>(wk, wqkT_bf + 256 * 512, DDIM, WP);
    cvt_bf16_k<<<(DDIM * DDIM) / 2048, 256, 0, stream>>>(wv_w, wv_bf);

    // enc = attn @ w_out^T + b_out + dense  (fp32 + bf16)
    gemm_mfma_ntb<<<dim3(NSEQ / 64, DDIM / 128, 1), 256, 0, stream>>>(
        attn_bf, INNER, 0, wout_bf, INNER, 0, ws + OFF_ENC, enc_bf, DDIM, 0,
        INNER, b_out, dense, nullptr, nullptr, 0);

    // qke = enc @ [wq|wk] -> bf16
    gemm_mfma_ntb<<<dim3(NSEQ / 64, 512 / 128, 1), 256, 0, stream>>>(
        enc_bf, DDIM, 0, wqkT_bf, DDIM, 0, nullptr, qke_bf, 512, 0,
        DDIM, nullptr, nullptr, nullptr, nullptr, 0);

    edge2_k<<<E / 32, 256, 0, stream>>>(qke_bf, adj_rows, adj_cols, adj_vals, A_raw);
    alpha_k<<<1, 1024, 0, stream>>>(A_raw, ws + OFF_ALPHA);

    // out = gated_blend(alpha, dense @ wv^T + wv_b, enc)  -- fused final
    gemm_mfma_ntb<<<dim3(NSEQ / 64, DDIM / 128, 1), 256, 0, stream>>>(
        dense_bf, DDIM, 0, wv_bf, DDIM, 0, out, nullptr, DDIM, 0,
        DDIM, wv_b, ws + OFF_ENC, ws + OFF_ALPHA, nullptr, 2);
}

// Round 12
// 528.044 us; speedup vs baseline: 3.1548x; 3.1548x over previous
//
#include <hip/hip_runtime.h>
#include <hip/hip_bf16.h>

// Problem constants (fixed by reference)
#define NSEQ 8192
#define DDIM 512
#define HEADS 8
#define DH 64
#define MLM 256
#define LSUB 32          // NSEQ / MLM
#define WP 256
#define KCONV 33
#define INNER 512        // HEADS*DH
#define QKV_LD 1536

// ---------------- workspace layout (float offsets) ----------------
static const size_t OFF_QKVBF  = 0;          // bf16 8192*1536 = 6,291,456 fl
static const size_t OFF_VT     = 6291456;    // bf16 8*64*8192 = 2,097,152 fl
static const size_t OFF_SC     = 8388608;    // bf16 exp-scores 8*256*8192 (ends 16,777,216)
// pinv overlays inside SC (alive only after scores consumed):
#define PS (8388608)
static const size_t A2R_H = PS + 0;        // each square buf: 262,144 fl (8*256*256 bf16)
static const size_t Z0R_H = PS + 524288;
static const size_t Z0T_H = PS + 1048576;
static const size_t Z1R_H = PS + 1572864;
static const size_t Z1T_H = PS + 2097152;
static const size_t PR_H  = PS + 2621440;
static const size_t PT_H  = PS + 3145728;
static const size_t T1T_H = PS + 3670016;
static const size_t T2T_H = PS + 4194304;
static const size_t A3VT_H= PS + 4718592;  // 65,536 fl
static const size_t A2F32 = PS + 4849664;  // fp32 8*256*256 = 524,288 fl
// after SC:
static const size_t OFF_ATTNBF = 16777216;   // bf16 8192*512 = 2,097,152 fl
static const size_t OFF_PART   = 18874368;   // fp32 pv3 partials 16*8*256*64 = 2,097,152 fl
// enc overlays dead qkv_bf region:
static const size_t OFF_ENC    = 0;          // fp32 8192*512 = 4,194,304 fl
static const size_t OFF_ENCBF  = 4194304;    // bf16 8192*512 = 2,097,152 fl
static const size_t OFF_QKE    = 6291456;    // bf16 8192*512 (vT dead)
// tail region:
static const size_t OFF_DENSEBF= 20971520;   // bf16 8192*512
static const size_t OFF_WQKVBF = 23068672;   // bf16 1536*512
static const size_t OFF_WOUTBF = 23461888;   // bf16 512*512
static const size_t OFF_WQKT   = 23592960;   // bf16 512*512 (wq^T | wk^T)
static const size_t OFF_WVBF   = 23724032;   // bf16 512*512
static const size_t OFF_QL     = 23855104;   // fp32 8*256*64
static const size_t OFF_KL     = 23986176;   // fp32 8*256*64
static const size_t OFF_QLBF   = 24117248;   // bf16 8*256*64
static const size_t OFF_KLSBF  = 24182784;   // bf16 8*256*64 (k_l * 0.125)
static const size_t OFF_BBT    = 24248320;   // bf16 8*64*256
static const size_t OFF_SCAL   = 24313856;   // 2 uints
static const size_t OFF_ALPHA  = 24313872;   // 8192 fp32
static const size_t OFF_DEN3   = 24322064;   // 2048 fp32

__device__ __forceinline__ float bf2f(unsigned short u) {
    return __uint_as_float(((unsigned int)u) << 16);
}
__device__ __forceinline__ unsigned short f2bf(float x) {
    unsigned int u = __float_as_uint(x);
    u += 0x7FFFu + ((u >> 16) & 1u);   // RNE
    return (unsigned short)(u >> 16);
}

typedef __attribute__((ext_vector_type(8))) short bf16x8;
typedef __attribute__((ext_vector_type(4))) float f32x4;

__device__ __forceinline__ void gload_lds16(const void* g, void* l) {
    __builtin_amdgcn_global_load_lds(
        (const __attribute__((address_space(1))) unsigned int*)g,
        (__attribute__((address_space(3))) unsigned int*)l, 16, 0, 0);
}

// ---------------- fp32 -> bf16 conversion (8 elems/thread) ----------------
__global__ __launch_bounds__(256) void cvt_bf16_k(
    const float* __restrict__ in, unsigned short* __restrict__ out)
{
    size_t i = ((size_t)blockIdx.x * 256 + threadIdx.x) * 8;
    float4 a = *reinterpret_cast<const float4*>(in + i);
    float4 b = *reinterpret_cast<const float4*>(in + i + 4);
    uint4 p;
    p.x = (unsigned int)f2bf(a.x) | ((unsigned int)f2bf(a.y) << 16);
    p.y = (unsigned int)f2bf(a.z) | ((unsigned int)f2bf(a.w) << 16);
    p.z = (unsigned int)f2bf(b.x) | ((unsigned int)f2bf(b.y) << 16);
    p.w = (unsigned int)f2bf(b.z) | ((unsigned int)f2bf(b.w) << 16);
    *reinterpret_cast<uint4*>(out + i) = p;
}

// ---------------- transpose + convert: out[c][r] = bf16(in[r][c]) ----------
__global__ __launch_bounds__(256) void tcvt_bf16_k(
    const float* __restrict__ in, unsigned short* __restrict__ out, int R, int C)
{
    int idx = blockIdx.x * 256 + threadIdx.x;
    if (idx < R * C) {
        int oc = idx / R;
        int orow = idx % R;
        out[idx] = f2bf(in[(size_t)orow * C + oc]);
    }
}

// ===== batched bf16 MFMA NT GEMM, 64x128 tile, BK=64 =====
// C[b,m,n] = sum_k A[b,m,k]*B[b,n,k]; 4 waves (2x2), wave = 32x64.
// epi: 0 none, 1 exp, 2 gated-final-blend, 3 exp + den row-sum atomic
__global__ __launch_bounds__(256) void gemm_mfma_ntb(
    const unsigned short* __restrict__ A, int lda, size_t sA,
    const unsigned short* __restrict__ B, int ldb, size_t sB,
    float* __restrict__ C, unsigned short* __restrict__ Cbf, int ldc, size_t sC,
    int K, const float* __restrict__ bias, const float* __restrict__ addsrc,
    const float* __restrict__ alphav, float* __restrict__ denv, int epi)
{
    __shared__ __align__(16) unsigned short As[64 * 64];
    __shared__ __align__(16) unsigned short Bs[128 * 64];
    const int tid = threadIdx.x;
    const int wave = tid >> 6, lane = tid & 63;
    const int l15 = lane & 15, l4 = lane >> 4;
    const int wm = wave >> 1, wn = wave & 1;
    const size_t bm = (size_t)blockIdx.x * 64;
    const size_t bn = (size_t)blockIdx.y * 128;
    const int z = blockIdx.z;
    const unsigned short* Ab = A + (size_t)z * sA;
    const unsigned short* Bb = B + (size_t)z * sB;
    const int swzr = (l15 & 7) << 3;
    f32x4 acc[2][4] = {};
    for (int k0 = 0; k0 < K; k0 += 64) {
        __syncthreads();
#pragma unroll
        for (int c2 = 0; c2 < 2; ++c2) {       // A: 64x64 = 512 x 16B
            int id = c2 * 256 + tid;
            int row = id >> 3;
            int cg = ((id & 7) ^ (row & 7)) << 3;
            gload_lds16(Ab + (bm + row) * (size_t)lda + k0 + cg, As + id * 8);
        }
#pragma unroll
        for (int c2 = 0; c2 < 4; ++c2) {       // B: 128x64 = 1024 x 16B
            int id = c2 * 256 + tid;
            int row = id >> 3;
            int cg = ((id & 7) ^ (row & 7)) << 3;
            gload_lds16(Bb + (bn + row) * (size_t)ldb + k0 + cg, Bs + id * 8);
        }
        __syncthreads();
#pragma unroll
        for (int c = 0; c < 2; ++c) {
            bf16x8 af[2], bfv[4];
#pragma unroll
            for (int i = 0; i < 2; ++i)
                af[i] = *reinterpret_cast<const bf16x8*>(
                    &As[(wm * 32 + i * 16 + l15) * 64 + ((c * 32 + l4 * 8) ^ swzr)]);
#pragma unroll
            for (int j = 0; j < 4; ++j)
                bfv[j] = *reinterpret_cast<const bf16x8*>(
                    &Bs[(wn * 64 + j * 16 + l15) * 64 + ((c * 32 + l4 * 8) ^ swzr)]);
#pragma unroll
            for (int i = 0; i < 2; ++i)
#pragma unroll
                for (int j = 0; j < 4; ++j)
                    acc[i][j] = __builtin_amdgcn_mfma_f32_16x16x32_bf16(
                        af[i], bfv[j], acc[i][j], 0, 0, 0);
        }
    }
    float* Cz = C ? C + (size_t)z * sC : nullptr;
    unsigned short* Cbz = Cbf ? Cbf + (size_t)z * sC : nullptr;
    if (epi == 3) {
        // exp + bf16 store + per-row denominator accumulation
#pragma unroll
        for (int i = 0; i < 2; ++i)
#pragma unroll
            for (int r = 0; r < 4; ++r) {
                size_t row = bm + wm * 32 + i * 16 + l4 * 4 + r;
                float s = 0.f;
#pragma unroll
                for (int j = 0; j < 4; ++j) {
                    size_t col = bn + wn * 64 + j * 16 + l15;
                    float e = __expf(acc[i][j][r]);
                    s += e;
                    Cbz[row * (size_t)ldc + col] = f2bf(e);
                }
                s += __shfl_xor(s, 1); s += __shfl_xor(s, 2);
                s += __shfl_xor(s, 4); s += __shfl_xor(s, 8);
                if (l15 == 0) atomicAdd(denv + (size_t)z * MLM + row, s);
            }
        return;
    }
#pragma unroll
    for (int i = 0; i < 2; ++i)
#pragma unroll
        for (int j = 0; j < 4; ++j)
#pragma unroll
            for (int r = 0; r < 4; ++r) {
                size_t row = bm + wm * 32 + i * 16 + l4 * 4 + r;
                size_t col = bn + wn * 64 + j * 16 + l15;
                float v = acc[i][j][r];
                if (bias) v += bias[col];
                if (epi == 2) {
                    float xl = alphav[row] * v;
                    float w = 1.f / (1.f + __expf(xl));
                    float sq = w * w;
                    v = xl * 2.f * sq + 2.f * addsrc[row * (size_t)ldc + col] * (1.f - sq);
                    Cz[row * (size_t)ldc + col] = v;
                } else {
                    if (addsrc) v += addsrc[row * (size_t)ldc + col];
                    if (epi == 1) v = __expf(v);
                    if (Cz)  Cz[row * (size_t)ldc + col] = v;
                    if (Cbz) Cbz[row * (size_t)ldc + col] = f2bf(v);
                }
            }
}

// ===== bf16 NT GEMM for pinv: C = beta*(A@B) + alpha*A =====
// A row-major [MxK]; B^T row-major [NxK].  64x64 tile, 4 waves 2x2, wave 32x32.
// Outputs: optional row-major Crh, optional transposed Cth (both bf16).
__global__ __launch_bounds__(256) void bmm_h(
    const unsigned short* __restrict__ Ah, const unsigned short* __restrict__ Bh,
    unsigned short* __restrict__ Crh, unsigned short* __restrict__ Cth,
    int M, int N, int K, int ntn, float alpha, float beta)
{
    __shared__ __align__(16) unsigned short LAh[64 * 64];
    __shared__ __align__(16) unsigned short LBh[64 * 64];
    const int tid = threadIdx.x;
    const int wave = tid >> 6, lane = tid & 63;
    const int l15 = lane & 15, l4 = lane >> 4;
    const int wm = wave >> 1, wn = wave & 1;
    const int b = blockIdx.y;
    const int tm = blockIdx.x / ntn, tn = blockIdx.x % ntn;
    const unsigned short* Ahb = Ah + (size_t)b * M * K;
    const unsigned short* Bhb = Bh + (size_t)b * N * K;
    const int swzr = (l15 & 7) << 3;
    f32x4 acc[2][2] = {};
    for (int k0 = 0; k0 < K; k0 += 64) {
        __syncthreads();
#pragma unroll
        for (int c2 = 0; c2 < 2; ++c2) {
            int id = c2 * 256 + tid;
            int row = id >> 3;
            int cg = ((id & 7) ^ (row & 7)) << 3;
            gload_lds16(Ahb + (size_t)(tm * 64 + row) * K + k0 + cg, LAh + id * 8);
            gload_lds16(Bhb + (size_t)(tn * 64 + row) * K + k0 + cg, LBh + id * 8);
        }
        __syncthreads();
#pragma unroll
        for (int c = 0; c < 2; ++c) {
            bf16x8 ah[2], bh[2];
#pragma unroll
            for (int i = 0; i < 2; ++i)
                ah[i] = *reinterpret_cast<const bf16x8*>(
                    &LAh[(wm * 32 + i * 16 + l15) * 64 + ((c * 32 + l4 * 8) ^ swzr)]);
#pragma unroll
            for (int j = 0; j < 2; ++j)
                bh[j] = *reinterpret_cast<const bf16x8*>(
                    &LBh[(wn * 32 + j * 16 + l15) * 64 + ((c * 32 + l4 * 8) ^ swzr)]);
#pragma unroll
            for (int i = 0; i < 2; ++i)
#pragma unroll
                for (int j = 0; j < 2; ++j)
                    acc[i][j] = __builtin_amdgcn_mfma_f32_16x16x32_bf16(ah[i], bh[j], acc[i][j], 0, 0, 0);
        }
    }
    unsigned short* Crhb = Crh ? Crh + (size_t)b * M * N : nullptr;
    unsigned short* Cthb = Cth ? Cth + (size_t)b * M * N : nullptr;
#pragma unroll
    for (int i = 0; i < 2; ++i)
#pragma unroll
        for (int j = 0; j < 2; ++j)
#pragma unroll
            for (int r = 0; r < 4; ++r) {
                int row = tm * 64 + wm * 32 + i * 16 + l4 * 4 + r;
                int col = tn * 64 + wn * 32 + j * 16 + l15;
                float v = beta * acc[i][j][r];
                if (alpha != 0.f)
                    v += alpha * bf2f(Ahb[(size_t)row * K + col]);   // square (M==K) only
                unsigned short hi = f2bf(v);
                if (Crhb) Crhb[(size_t)row * N + col] = hi;
                if (Cthb) Cthb[(size_t)col * M + row] = hi;
            }
}

// ===== pv3: partials[kc][h][i][d] = sum_{j in chunk} P[h,i,j]*vT[h,d,j] =====
__global__ __launch_bounds__(256) void pv3_mfma(
    const unsigned short* __restrict__ sc, const unsigned short* __restrict__ vT,
    float* __restrict__ part)
{
    __shared__ __align__(16) unsigned short As[64 * 64];
    __shared__ __align__(16) unsigned short Bs[64 * 64];
    const int tid = threadIdx.x;
    const int wave = tid >> 6, lane = tid & 63;
    const int l15 = lane & 15, l4 = lane >> 4;
    const int wm = wave >> 1, wn = wave & 1;
    const int it = blockIdx.x, kc = blockIdx.y, h = blockIdx.z;
    const unsigned short* Ap = sc + (size_t)h * MLM * NSEQ + (size_t)(it * 64) * NSEQ + kc * 512;
    const unsigned short* Bp = vT + (size_t)h * DH * NSEQ + kc * 512;
    const int swzr = (l15 & 7) << 3;
    f32x4 acc[2][2] = {};
    for (int k0 = 0; k0 < 512; k0 += 64) {
        __syncthreads();
#pragma unroll
        for (int c2 = 0; c2 < 2; ++c2) {
            int id = c2 * 256 + tid;
            int row = id >> 3;
            int cg = ((id & 7) ^ (row & 7)) << 3;
            gload_lds16(Ap + (size_t)row * NSEQ + k0 + cg, As + id * 8);
        }
#pragma unroll
        for (int c2 = 0; c2 < 2; ++c2) {
            int id = c2 * 256 + tid;
            int row = id >> 3;
            int cg = ((id & 7) ^ (row & 7)) << 3;
            gload_lds16(Bp + (size_t)row * NSEQ + k0 + cg, Bs + id * 8);
        }
        __syncthreads();
#pragma unroll
        for (int ks = 0; ks < 2; ++ks) {
            bf16x8 af[2], bfv[2];
#pragma unroll
            for (int i = 0; i < 2; ++i)
                af[i] = *reinterpret_cast<const bf16x8*>(
                    &As[(wm * 32 + i * 16 + l15) * 64 + ((ks * 32 + l4 * 8) ^ swzr)]);
#pragma unroll
            for (int j = 0; j < 2; ++j)
                bfv[j] = *reinterpret_cast<const bf16x8*>(
                    &Bs[(wn * 32 + j * 16 + l15) * 64 + ((ks * 32 + l4 * 8) ^ swzr)]);
#pragma unroll
            for (int i = 0; i < 2; ++i)
#pragma unroll
                for (int j = 0; j < 2; ++j)
                    acc[i][j] = __builtin_amdgcn_mfma_f32_16x16x32_bf16(af[i], bfv[j], acc[i][j], 0, 0, 0);
        }
    }
    float* Cp = part + ((size_t)(kc * 8 + h) * MLM + it * 64) * DH;
#pragma unroll
    for (int i = 0; i < 2; ++i)
#pragma unroll
        for (int j = 0; j < 2; ++j)
#pragma unroll
            for (int r = 0; r < 4; ++r)
                Cp[(wm * 32 + i * 16 + l4 * 4 + r) * DH + wn * 32 + j * 16 + l15] = acc[i][j][r];
}

// ===== fused a1: QK + exp-softmax + PV (2-phase P) + conv, writes bf16 attn =====
// LDS peak 28KB: A(8KB) -> P(16KB) -> att(16KB)+vbuf(12KB); kls/bbT from L2.
__global__ __launch_bounds__(256) void a1_fused(
    const unsigned short* __restrict__ qkvbf,
    const unsigned short* __restrict__ kls,     // [h][256][64] (k_l * 0.125)
    const unsigned short* __restrict__ bbT,     // [h][64][256]
    const float* __restrict__ kern,
    unsigned short* __restrict__ attnbf)
{
    __shared__ __align__(16) unsigned short lds[14336];  // 28 KB
    __shared__ float den[2][64];
    __shared__ float kc_s[KCONV];
    const int tid = threadIdx.x;
    const int wave = tid >> 6, lane = tid & 63;
    const int l15 = lane & 15, l4 = lane >> 4;
    const int wm = wave >> 1, wn = wave & 1;
    const int n0 = blockIdx.x * 64;
    const int h = blockIdx.y;
    const int swzr = (l15 & 7) << 3;

    if (tid < KCONV) kc_s[tid] = kern[h * KCONV + tid];
    // stage A (q rows 64x64) only; kls fragments come straight from L2
#pragma unroll
    for (int c2 = 0; c2 < 2; ++c2) {
        int id = c2 * 256 + tid;
        int row = id >> 3, cg = ((id & 7) ^ (row & 7)) << 3;
        gload_lds16(qkvbf + (size_t)(n0 + row) * QKV_LD + h * DH + cg, lds + id * 8);
    }
    __syncthreads();
    // QK: S = q . kls^T  (64 x 256), wave tile 32 x 128
    const unsigned short* klsh = kls + (size_t)h * (MLM * DH);
    f32x4 acc[2][8] = {};
#pragma unroll
    for (int c = 0; c < 2; ++c) {
        bf16x8 af[2], bv[8];
#pragma unroll
        for (int i = 0; i < 2; ++i) {
            int row = wm * 32 + i * 16 + l15;
            af[i] = *reinterpret_cast<const bf16x8*>(&lds[row * 64 + ((c * 32 + l4 * 8) ^ swzr)]);
        }
#pragma unroll
        for (int j = 0; j < 8; ++j) {
            int brow = wn * 128 + j * 16 + l15;
            bv[j] = *reinterpret_cast<const bf16x8*>(&klsh[brow * 64 + c * 32 + l4 * 8]);
        }
#pragma unroll
        for (int i = 0; i < 2; ++i)
#pragma unroll
            for (int j = 0; j < 8; ++j)
                acc[i][j] = __builtin_amdgcn_mfma_f32_16x16x32_bf16(af[i], bv[j], acc[i][j], 0, 0, 0);
    }
    __syncthreads();   // all A reads complete -> P may overlay
    // exp in place (scores tiny: no max) + row sums
    float rs[2][4] = {};
#pragma unroll
    for (int i = 0; i < 2; ++i)
#pragma unroll
        for (int j = 0; j < 8; ++j)
#pragma unroll
            for (int r = 0; r < 4; ++r) {
                float e = __expf(acc[i][j][r]);
                acc[i][j][r] = e;
                rs[i][r] += e;
            }
#pragma unroll
    for (int i = 0; i < 2; ++i)
#pragma unroll
        for (int r = 0; r < 4; ++r) {
            float s = rs[i][r];
            s += __shfl_xor(s, 1); s += __shfl_xor(s, 2);
            s += __shfl_xor(s, 4); s += __shfl_xor(s, 8);
            if (l15 == 0) den[wn][wm * 32 + i * 16 + l4 * 4 + r] = s;
        }
    // PV in two 128-wide k-phases; P buffer = lds[0..8192) (16 KB)
    f32x4 acc2[2][2] = {};
    const unsigned short* bbh = bbT + (size_t)h * DH * MLM;
#pragma unroll
    for (int ph = 0; ph < 2; ++ph) {
        if (wn == ph) {
#pragma unroll
            for (int i = 0; i < 2; ++i)
#pragma unroll
                for (int j = 0; j < 8; ++j)
#pragma unroll
                    for (int r = 0; r < 4; ++r) {
                        int row = wm * 32 + i * 16 + l4 * 4 + r;
                        int col = j * 16 + l15;          // local col 0..127
                        lds[row * 128 + (col ^ ((row & 7) << 3))] = f2bf(acc[i][j][r]);
                    }
        }
        __syncthreads();
#pragma unroll
        for (int k = 0; k < 128; k += 32) {
            bf16x8 af2[2], bv2[2];
#pragma unroll
            for (int i = 0; i < 2; ++i) {
                int row = wm * 32 + i * 16 + l15;
                af2[i] = *reinterpret_cast<const bf16x8*>(
                    &lds[row * 128 + ((k + l4 * 8) ^ ((row & 7) << 3))]);
            }
#pragma unroll
            for (int j = 0; j < 2; ++j) {
                int d = wn * 32 + j * 16 + l15;
                bv2[j] = *reinterpret_cast<const bf16x8*>(&bbh[d * MLM + ph * 128 + k + l4 * 8]);
            }
#pragma unroll
            for (int i = 0; i < 2; ++i)
#pragma unroll
                for (int j = 0; j < 2; ++j)
                    acc2[i][j] = __builtin_amdgcn_mfma_f32_16x16x32_bf16(af2[i], bv2[j], acc2[i][j], 0, 0, 0);
        }
        __syncthreads();   // P reads done before next-phase writes / att overlay
    }
    // normalized PV -> LDS fp32 att[64][64] at lds[0]; v window 96x64 at lds[8192]
    float* att = reinterpret_cast<float*>(lds);              // 16 KB
    unsigned short* vbuf = &lds[8192];                       // 12 KB
#pragma unroll
    for (int i = 0; i < 2; ++i)
#pragma unroll
        for (int r = 0; r < 4; ++r) {
            int row = wm * 32 + i * 16 + l4 * 4 + r;
            float inv = 1.f / (den[0][row] + den[1][row]);
#pragma unroll
            for (int j = 0; j < 2; ++j)
                att[row * 64 + wn * 32 + j * 16 + l15] = acc2[i][j][r] * inv;
        }
#pragma unroll
    for (int s = 0; s < 6; ++s) {
        int id = s * 256 + tid;
        int r = id >> 4, c4 = (id & 15) * 4;
        int n = n0 - 16 + r;
        ushort4 u = {0, 0, 0, 0};
        if (n >= 0 && n < NSEQ)
            u = *reinterpret_cast<const ushort4*>(qkvbf + (size_t)n * QKV_LD + 1024 + h * 64 + c4);
        *reinterpret_cast<ushort4*>(vbuf + r * 64 + c4) = u;
    }
    __syncthreads();
    // conv: each thread owns 16 rows of one column
    const int col = tid & 63, rowg = tid >> 6;
    float vwin[48];
#pragma unroll
    for (int t = 0; t < 48; ++t) vwin[t] = bf2f(vbuf[(rowg * 16 + t) * 64 + col]);
#pragma unroll
    for (int rr = 0; rr < 16; ++rr) {
        float cv = 0.f;
#pragma unroll
        for (int t = 0; t < KCONV; ++t) cv += kc_s[t] * vwin[rr + t];
        int row = rowg * 16 + rr;
        attnbf[(size_t)(n0 + row) * INNER + h * DH + col] = f2bf(att[row * 64 + col] + cv);
    }
}

// ------------- landmark means from bf16 qkv (+ bf16 copies) -------------
__global__ __launch_bounds__(64) void landmark2_k(
    const unsigned short* __restrict__ qkvbf, float* __restrict__ q_l, float* __restrict__ k_l,
    unsigned short* __restrict__ ql_bf, unsigned short* __restrict__ kls_bf)
{
    int m = blockIdx.x, h = blockIdx.y, d = threadIdx.x;
    float sq = 0.f, sk = 0.f;
    for (int i = 0; i < LSUB; ++i) {
        size_t n = (size_t)m * LSUB + i;
        sq += bf2f(qkvbf[n * QKV_LD + h * DH + d]);
        sk += bf2f(qkvbf[n * QKV_LD + 512 + h * DH + d]);
    }
    float qv = sq * (0.125f / (float)LSUB);
    float kv = sk * (1.f / (float)LSUB);
    size_t o = ((size_t)h * MLM + m) * DH + d;
    q_l[o] = qv; k_l[o] = kv;
    ql_bf[o] = f2bf(qv);
    kls_bf[o] = f2bf(kv * 0.125f);
}

// ------------- v transpose: vT[h][d][n] = qkv_bf[n][1024+h*64+d] -------------
__global__ __launch_bounds__(256) void vt_k(
    const unsigned short* __restrict__ qkvbf, unsigned short* __restrict__ vT)
{
    __shared__ unsigned short tile[128][72];
    const int t = threadIdx.x;
    const int n0 = blockIdx.x * 128;
    const int h = blockIdx.y;
#pragma unroll
    for (int s = 0; s < 4; ++s) {
        int cid = s * 256 + t;
        int row = cid >> 3, ch = (cid & 7) * 8;
        uint4 v = *reinterpret_cast<const uint4*>(
            qkvbf + (size_t)(n0 + row) * QKV_LD + 1024 + h * 64 + ch);
        *reinterpret_cast<uint4*>(&tile[row][ch]) = v;
    }
    __syncthreads();
#pragma unroll
    for (int s = 0; s < 4; ++s) {
        int cid = s * 256 + t;
        int d = cid >> 4, nch = (cid & 15) * 8;
        unsigned short o[8];
#pragma unroll
        for (int i = 0; i < 8; ++i) o[i] = tile[nch + i][d];
        *reinterpret_cast<uint4*>(vT + (size_t)h * DH * NSEQ + (size_t)d * NSEQ + n0 + nch) =
            *reinterpret_cast<uint4*>(o);
    }
}

// ------------- a2 = softmax(q_l @ k_l^T) rows -------------
__global__ __launch_bounds__(256) void a2_k(
    const float* __restrict__ q_l, const float* __restrict__ k_l, float* __restrict__ a2)
{
    int i = blockIdx.x, h = blockIdx.y, t = threadIdx.x;
    __shared__ float ql[64];
    __shared__ float red[256];
    if (t < 64) ql[t] = q_l[((size_t)h * MLM + i) * DH + t];
    __syncthreads();
    const float* kr = k_l + ((size_t)h * MLM + t) * DH;
    float s = 0.f;
#pragma unroll
    for (int d = 0; d < 64; d += 4) {
        float4 kv = *reinterpret_cast<const float4*>(kr + d);
        s += kv.x * ql[d] + kv.y * ql[d + 1] + kv.z * ql[d + 2] + kv.w * ql[d + 3];
    }
    red[t] = s; __syncthreads();
    for (int off = 128; off > 0; off >>= 1) { if (t < off) red[t] = fmaxf(red[t], red[t + off]); __syncthreads(); }
    float m = red[0]; __syncthreads();
    float e = __expf(s - m);
    red[t] = e; __syncthreads();
    for (int off = 128; off > 0; off >>= 1) { if (t < off) red[t] += red[t + off]; __syncthreads(); }
    a2[(((size_t)h * MLM + i) * MLM) + t] = e / red[0];
}

// ------------- global max of row/col abs-sums of a2 -------------
__global__ __launch_bounds__(256) void absmax_k(
    const float* __restrict__ a2, unsigned int* __restrict__ scal)
{
    int b = blockIdx.x, t = threadIdx.x;
    __shared__ float red[256];
    float sum = 0.f;
    if (b < 8) {
        const float* r = a2 + ((size_t)b * MLM + t) * MLM;
        for (int j = 0; j < MLM; ++j) sum += fabsf(r[j]);
    } else {
        int h = b - 8;
        for (int i = 0; i < MLM; ++i) sum += fabsf(a2[((size_t)h * MLM + i) * MLM + t]);
    }
    red[t] = sum; __syncthreads();
    for (int off = 128; off > 0; off >>= 1) { if (t < off) red[t] = fmaxf(red[t], red[t + off]); __syncthreads(); }
    if (t == 0) atomicMax(scal + (b < 8 ? 0 : 1), __float_as_uint(red[0]));
}

// ------------- zinit2: a2 + z0 (row & T) to bf16 -------------
__global__ __launch_bounds__(256) void zinit2_k(
    const float* __restrict__ a2, const unsigned int* __restrict__ scal,
    unsigned short* __restrict__ a2h,
    unsigned short* __restrict__ zrh, unsigned short* __restrict__ zth)
{
    int idx = blockIdx.x * 256 + threadIdx.x;
    float inv = 1.f / (__uint_as_float(scal[0]) * __uint_as_float(scal[1]));
    int h = idx >> 16, rem = idx & 65535, i = rem >> 8, j = rem & 255;
    float aij = a2[idx];
    a2h[idx] = f2bf(aij);
    zth[idx] = f2bf(aij * inv);                              // z0T[i][j] = a2[i][j]*inv
    zrh[idx] = f2bf(a2[((size_t)h << 16) + (j << 8) + i] * inv);  // z0row[i][j] = a2[j][i]*inv
}

// ------------- red3: sum partials, divide, write a3v^T bf16 -------------
__global__ __launch_bounds__(256) void red3_k(
    const float* __restrict__ part, const float* __restrict__ den3,
    unsigned short* __restrict__ a3vth)
{
    int o = blockIdx.x * 256 + threadIdx.x;   // [8][256][64]
    float s = 0.f;
#pragma unroll
    for (int kc = 0; kc < 16; ++kc) s += part[(size_t)kc * 131072 + o];
    s /= den3[o >> 6];
    int h = o >> 14, i = (o >> 6) & 255, d = o & 63;
    a3vth[(h << 14) + (d << 8) + i] = f2bf(s);
}

// ------------- sparse edge scores: 8 lanes/edge, 32 dims/lane -------------
__global__ __launch_bounds__(256) void edge2_k(
    const unsigned short* __restrict__ qke,
    const int* __restrict__ rows, const int* __restrict__ cols,
    const float* __restrict__ vals, float* __restrict__ A_raw)
{
    const int e = blockIdx.x * 32 + (threadIdx.x >> 3);
    const int g = threadIdx.x & 7;
    const int r = rows[e], c = cols[e];
    const unsigned short* qr = qke + (size_t)r * 512 + g * 32;
    const unsigned short* kr = qke + (size_t)c * 512 + 256 + g * 32;
    float s = 0.f;
#pragma unroll
    for (int u = 0; u < 4; ++u) {
        uint4 qa = *reinterpret_cast<const uint4*>(qr + u * 8);
        uint4 ka = *reinterpret_cast<const uint4*>(kr + u * 8);
        unsigned int qw[4] = {qa.x, qa.y, qa.z, qa.w};
        unsigned int kw[4] = {ka.x, ka.y, ka.z, ka.w};
#pragma unroll
        for (int q = 0; q < 4; ++q) {
            s += bf2f((unsigned short)(qw[q] & 0xFFFF)) * bf2f((unsigned short)(kw[q] & 0xFFFF));
            s += bf2f((unsigned short)(qw[q] >> 16)) * bf2f((unsigned short)(kw[q] >> 16));
        }
    }
    s += __shfl_xor(s, 1); s += __shfl_xor(s, 2); s += __shfl_xor(s, 4);
    if (g == 0) atomicAdd(&A_raw[r], s * vals[e] * 0.0625f);
}

// ------------- alpha = softmax(A_raw) -------------
__global__ __launch_bounds__(1024) void alpha_k(
    const float* __restrict__ A_raw, float* __restrict__ alpha)
{
    __shared__ float red[1024];
    int t = threadIdx.x;
    float m = -1e30f;
    for (int i = t; i < NSEQ; i += 1024) m = fmaxf(m, A_raw[i]);
    red[t] = m; __syncthreads();
    for (int off = 512; off > 0; off >>= 1) { if (t < off) red[t] = fmaxf(red[t], red[t + off]); __syncthreads(); }
    m = red[0]; __syncthreads();
    float s = 0.f;
    for (int i = t; i < NSEQ; i += 1024) s += __expf(A_raw[i] - m);
    red[t] = s; __syncthreads();
    for (int off = 512; off > 0; off >>= 1) { if (t < off) red[t] += red[t + off]; __syncthreads(); }
    float inv = 1.f / red[0];
    for (int i = t; i < NSEQ; i += 1024) alpha[i] = __expf(A_raw[i] - m) * inv;
}

extern "C" void kernel_launch(void* const* d_in, const int* in_sizes, int n_in,
                              void* d_out, int out_size, void* d_ws, size_t ws_size,
                              hipStream_t stream)
{
    const float* dense      = (const float*)d_in[0];
    const int*   adj_rows   = (const int*)d_in[1];
    const int*   adj_cols   = (const int*)d_in[2];
    const float* adj_vals   = (const float*)d_in[3];
    const float* wq         = (const float*)d_in[4];
    const float* wk         = (const float*)d_in[5];
    const float* w_qkv      = (const float*)d_in[6];
    const float* w_out      = (const float*)d_in[7];
    const float* b_out      = (const float*)d_in[8];
    const float* res_kernel = (const float*)d_in[9];
    const float* wv_w       = (const float*)d_in[10];
    const float* wv_b       = (const float*)d_in[11];
    const int E = in_sizes[1];

    float* ws  = (float*)d_ws;
    float* out = (float*)d_out;
    float* A_raw = out + (size_t)NSEQ * DDIM;

    unsigned short* qkv_bf   = (unsigned short*)(ws + OFF_QKVBF);
    unsigned short* vT       = (unsigned short*)(ws + OFF_VT);
    unsigned short* sc       = (unsigned short*)(ws + OFF_SC);
    unsigned short* attn_bf  = (unsigned short*)(ws + OFF_ATTNBF);
    unsigned short* qke_bf   = (unsigned short*)(ws + OFF_QKE);
    unsigned short* dense_bf = (unsigned short*)(ws + OFF_DENSEBF);
    unsigned short* wqkv_bf  = (unsigned short*)(ws + OFF_WQKVBF);
    unsigned short* wout_bf  = (unsigned short*)(ws + OFF_WOUTBF);
    unsigned short* wqkT_bf  = (unsigned short*)(ws + OFF_WQKT);
    unsigned short* wv_bf    = (unsigned short*)(ws + OFF_WVBF);
    unsigned short* ql_bf    = (unsigned short*)(ws + OFF_QLBF);
    unsigned short* kls_bf   = (unsigned short*)(ws + OFF_KLSBF);
    unsigned short* bbT_bf   = (unsigned short*)(ws + OFF_BBT);
    unsigned short* enc_bf   = (unsigned short*)(ws + OFF_ENCBF);

#define U16(off) ((unsigned short*)(ws + (off)))

    (void)hipMemsetAsync(A_raw, 0, NSEQ * sizeof(float), stream);
    (void)hipMemsetAsync(ws + OFF_SCAL, 0, 2 * sizeof(unsigned int), stream);
    (void)hipMemsetAsync(ws + OFF_DEN3, 0, HEADS * MLM * sizeof(float), stream);

    // ---- input conversions ----
    cvt_bf16_k<<<(NSEQ * DDIM) / 2048, 256, 0, stream>>>(dense, dense_bf);
    cvt_bf16_k<<<(1536 * DDIM) / 2048, 256, 0, stream>>>(w_qkv, wqkv_bf);

    // qkv = dense @ w_qkv^T  -> bf16
    gemm_mfma_ntb<<<dim3(NSEQ / 64, 1536 / 128, 1), 256, 0, stream>>>(
        dense_bf, DDIM, 0, wqkv_bf, DDIM, 0, nullptr, qkv_bf, QKV_LD, 0,
        DDIM, nullptr, nullptr, nullptr, nullptr, 0);

    landmark2_k<<<dim3(MLM, HEADS), 64, 0, stream>>>(
        qkv_bf, ws + OFF_QL, ws + OFF_KL, ql_bf, kls_bf);
    vt_k<<<dim3(NSEQ / 128, HEADS), 256, 0, stream>>>(qkv_bf, vT);

    // ---- a3 pipeline (exp-scores + fused den accumulation) ----
    gemm_mfma_ntb<<<dim3(MLM / 64, NSEQ / 128, HEADS), 256, 0, stream>>>(
        ql_bf, DH, (size_t)MLM * DH, qkv_bf + 512, QKV_LD, DH,
        nullptr, sc, NSEQ, (size_t)MLM * NSEQ, DH, nullptr, nullptr, nullptr,
        ws + OFF_DEN3, 3);
    pv3_mfma<<<dim3(4, 16, HEADS), 256, 0, stream>>>(sc, vT, ws + OFF_PART);
    red3_k<<<512, 256, 0, stream>>>(ws + OFF_PART, ws + OFF_DEN3, U16(A3VT_H));

    a2_k<<<dim3(MLM, HEADS), 256, 0, stream>>>(ws + OFF_QL, ws + OFF_KL, ws + A2F32);
    absmax_k<<<16, 256, 0, stream>>>(ws + A2F32, (unsigned int*)(ws + OFF_SCAL));
    zinit2_k<<<(HEADS * MLM * MLM) / 256, 256, 0, stream>>>(
        ws + A2F32, (const unsigned int*)(ws + OFF_SCAL),
        U16(A2R_H), U16(Z0R_H), U16(Z0T_H));

    // pinv iterations (bf16 MFMA; Newton-Schulz is self-correcting)
    for (int it = 0; it < 6; ++it) {
        size_t zr_h = (it & 1) ? Z1R_H : Z0R_H;
        size_t zt_h = (it & 1) ? Z1T_H : Z0T_H;
        size_t or_h = (it & 1) ? Z0R_H : Z1R_H;
        size_t ot_h = (it & 1) ? Z0T_H : Z1T_H;
        bmm_h<<<dim3(16, HEADS), 256, 0, stream>>>(
            U16(A2R_H), U16(zt_h), U16(PR_H), U16(PT_H), 256, 256, 256, 4, 0.f, 1.f);
        bmm_h<<<dim3(16, HEADS), 256, 0, stream>>>(
            U16(PR_H), U16(PT_H), nullptr, U16(T1T_H), 256, 256, 256, 4, 7.f, -1.f);
        bmm_h<<<dim3(16, HEADS), 256, 0, stream>>>(
            U16(PR_H), U16(T1T_H), nullptr, U16(T2T_H), 256, 256, 256, 4, 15.f, -1.f);
        bmm_h<<<dim3(16, HEADS), 256, 0, stream>>>(
            U16(zr_h), U16(T2T_H), U16(or_h), U16(ot_h), 256, 256, 256, 4, 3.25f, -0.25f);
    }
    // bbT = (z @ a3v)^T = NT(a3vT, z_row)   [64 x 256]
    bmm_h<<<dim3(4, HEADS), 256, 0, stream>>>(
        U16(A3VT_H), U16(Z0R_H), bbT_bf, nullptr, 64, 256, 256, 4, 0.f, 1.f);

    // ---- fused a1 (QK + exp-softmax + PV + conv -> bf16 attn) ----
    a1_fused<<<dim3(NSEQ / 64, HEADS), 256, 0, stream>>>(
        qkv_bf, kls_bf, bbT_bf, res_kernel, attn_bf);

    // ---- late weights to bf16 ----
    cvt_bf16_k<<<(DDIM * INNER) / 2048, 256, 0, stream>>>(w_out, wout_bf);
    tcvt_bf16_k<<<(WP * DDIM + 255) / 256, 256, 0, stream>>>(wq, wqkT_bf, DDIM, WP);
    tcvt_bf16_k<<<(WP * DDIM + 255) / 256, 256, 0, stream>>>(wk, wqkT_bf + 256 * 512, DDIM, WP);
    cvt_bf16_k<<<(DDIM * DDIM) / 2048, 256, 0, stream>>>(wv_w, wv_bf);

    // enc = attn @ w_out^T + b_out + dense  (fp32 + bf16)
    gemm_mfma_ntb<<<dim3(NSEQ / 64, DDIM / 128, 1), 256, 0, stream>>>(
        attn_bf, INNER, 0, wout_bf, INNER, 0, ws + OFF_ENC, enc_bf, DDIM, 0,
        INNER, b_out, dense, nullptr, nullptr, 0);

    // qke = enc @ [wq|wk] -> bf16
    gemm_mfma_ntb<<<dim3(NSEQ / 64, 512 / 128, 1), 256, 0, stream>>>(
        enc_bf, DDIM, 0, wqkT_bf, DDIM, 0, nullptr, qke_bf, 512, 0,
        DDIM, nullptr, nullptr, nullptr, nullptr, 0);

    edge2_k<<<E / 32, 256, 0, stream>>>(qke_bf, adj_rows, adj_cols, adj_vals, A_raw);
    alpha_k<<<1, 1024, 0, stream>>>(A_raw, ws + OFF_ALPHA);

    // out = gated_blend(alpha, dense @ wv^T + wv_b, enc)  -- fused final
    gemm_mfma_ntb<<<dim3(NSEQ / 64, DDIM / 128, 1), 256, 0, stream>>>(
        dense_bf, DDIM, 0, wv_bf, DDIM, 0, out, nullptr, DDIM, 0,
        DDIM, wv_b, ws + OFF_ENC, ws + OFF_ALPHA, nullptr, 2);
}

// Round 13
// 497.333 us; speedup vs baseline: 3.3496x; 1.0618x over previous
//
#include <hip/hip_runtime.h>
#include <hip/hip_bf16.h>

// Problem constants (fixed by reference)
#define NSEQ 8192
#define DDIM 512
#define HEADS 8
#define DH 64
#define MLM 256
#define LSUB 32          // NSEQ / MLM
#define WP 256
#define KCONV 33
#define INNER 512        // HEADS*DH
#define QKV_LD 1536

// ---------------- workspace layout (float offsets) ----------------
static const size_t OFF_QKVBF  = 0;          // bf16 8192*1536 = 6,291,456 fl
static const size_t OFF_VT     = 6291456;    // bf16 8*64*8192 = 2,097,152 fl
static const size_t OFF_SC     = 8388608;    // bf16 exp-scores 8*256*8192 (ends 16,777,216)
// pinv overlays inside SC (alive only after scores consumed):
#define PS (8388608)
static const size_t A2R_H = PS + 0;        // each square buf: 262,144 fl (8*256*256 bf16)
static const size_t Z0R_H = PS + 524288;
static const size_t Z0T_H = PS + 1048576;
static const size_t Z1R_H = PS + 1572864;
static const size_t Z1T_H = PS + 2097152;
static const size_t PR_H  = PS + 2621440;
static const size_t PT_H  = PS + 3145728;
static const size_t T1T_H = PS + 3670016;
static const size_t T2T_H = PS + 4194304;
static const size_t A3VT_H= PS + 4718592;  // 65,536 fl
static const size_t A2F32 = PS + 4849664;  // fp32 8*256*256 = 524,288 fl
// after SC:
static const size_t OFF_ATTNBF = 16777216;   // bf16 8192*512 = 2,097,152 fl
static const size_t OFF_PART   = 18874368;   // fp32 pv3 partials 16*8*256*64 = 2,097,152 fl
// enc overlays dead qkv_bf region:
static const size_t OFF_ENC    = 0;          // fp32 8192*512 = 4,194,304 fl
static const size_t OFF_ENCBF  = 4194304;    // bf16 8192*512 = 2,097,152 fl
static const size_t OFF_QKE    = 6291456;    // bf16 8192*512 (vT dead)
// tail region:
static const size_t OFF_DENSEBF= 20971520;   // bf16 8192*512
static const size_t OFF_WQKVBF = 23068672;   // bf16 1536*512
static const size_t OFF_WOUTBF = 23461888;   // bf16 512*512
static const size_t OFF_WQKT   = 23592960;   // bf16 512*512 (wq^T | wk^T)
static const size_t OFF_WVBF   = 23724032;   // bf16 512*512
static const size_t OFF_QL     = 23855104;   // fp32 8*256*64
static const size_t OFF_KL     = 23986176;   // fp32 8*256*64
static const size_t OFF_QLBF   = 24117248;   // bf16 8*256*64
static const size_t OFF_KLSBF  = 24182784;   // bf16 8*256*64 (k_l * 0.125)
static const size_t OFF_BBT    = 24248320;   // bf16 8*64*256
static const size_t OFF_SCAL   = 24313856;   // 2 uints
static const size_t OFF_ALPHA  = 24313872;   // 8192 fp32
static const size_t OFF_DEN3   = 24322064;   // 2048 fp32

__device__ __forceinline__ float bf2f(unsigned short u) {
    return __uint_as_float(((unsigned int)u) << 16);
}
__device__ __forceinline__ unsigned short f2bf(float x) {
    unsigned int u = __float_as_uint(x);
    u += 0x7FFFu + ((u >> 16) & 1u);   // RNE
    return (unsigned short)(u >> 16);
}

typedef __attribute__((ext_vector_type(8))) short bf16x8;
typedef __attribute__((ext_vector_type(4))) float f32x4;

__device__ __forceinline__ void gload_lds16(const void* g, void* l) {
    __builtin_amdgcn_global_load_lds(
        (const __attribute__((address_space(1))) unsigned int*)g,
        (__attribute__((address_space(3))) unsigned int*)l, 16, 0, 0);
}

// ---------------- fp32 -> bf16 conversion (8 elems/thread) ----------------
__global__ __launch_bounds__(256) void cvt_bf16_k(
    const float* __restrict__ in, unsigned short* __restrict__ out)
{
    size_t i = ((size_t)blockIdx.x * 256 + threadIdx.x) * 8;
    float4 a = *reinterpret_cast<const float4*>(in + i);
    float4 b = *reinterpret_cast<const float4*>(in + i + 4);
    uint4 p;
    p.x = (unsigned int)f2bf(a.x) | ((unsigned int)f2bf(a.y) << 16);
    p.y = (unsigned int)f2bf(a.z) | ((unsigned int)f2bf(a.w) << 16);
    p.z = (unsigned int)f2bf(b.x) | ((unsigned int)f2bf(b.y) << 16);
    p.w = (unsigned int)f2bf(b.z) | ((unsigned int)f2bf(b.w) << 16);
    *reinterpret_cast<uint4*>(out + i) = p;
}

// ---- merged late-weight conversion: wout cvt | wv cvt | wq tcvt | wk tcvt ----
__global__ __launch_bounds__(256) void wcvt_k(
    const float* __restrict__ w_out, unsigned short* __restrict__ wout_bf,
    const float* __restrict__ wv_w,  unsigned short* __restrict__ wv_bf,
    const float* __restrict__ wq,    const float* __restrict__ wk,
    unsigned short* __restrict__ wqkT_bf)
{
    int b = blockIdx.x;
    if (b < 128) {                     // wout: 512*512, 8/thread
        size_t i = ((size_t)b * 256 + threadIdx.x) * 8;
        float4 a = *reinterpret_cast<const float4*>(w_out + i);
        float4 c = *reinterpret_cast<const float4*>(w_out + i + 4);
        uint4 p;
        p.x = (unsigned int)f2bf(a.x) | ((unsigned int)f2bf(a.y) << 16);
        p.y = (unsigned int)f2bf(a.z) | ((unsigned int)f2bf(a.w) << 16);
        p.z = (unsigned int)f2bf(c.x) | ((unsigned int)f2bf(c.y) << 16);
        p.w = (unsigned int)f2bf(c.z) | ((unsigned int)f2bf(c.w) << 16);
        *reinterpret_cast<uint4*>(wout_bf + i) = p;
    } else if (b < 256) {              // wv: 512*512, 8/thread
        size_t i = ((size_t)(b - 128) * 256 + threadIdx.x) * 8;
        float4 a = *reinterpret_cast<const float4*>(wv_w + i);
        float4 c = *reinterpret_cast<const float4*>(wv_w + i + 4);
        uint4 p;
        p.x = (unsigned int)f2bf(a.x) | ((unsigned int)f2bf(a.y) << 16);
        p.y = (unsigned int)f2bf(a.z) | ((unsigned int)f2bf(a.w) << 16);
        p.z = (unsigned int)f2bf(c.x) | ((unsigned int)f2bf(c.y) << 16);
        p.w = (unsigned int)f2bf(c.z) | ((unsigned int)f2bf(c.w) << 16);
        *reinterpret_cast<uint4*>(wv_bf + i) = p;
    } else if (b < 768) {              // wq^T: out[c][r]=wq[r][c], 512*256 outputs
        int idx = (b - 256) * 256 + threadIdx.x;     // linear in out [256][512]
        int oc = idx / 512;                           // out row (former col, 0..255)
        int orow = idx % 512;                         // out col (former row)
        wqkT_bf[idx] = f2bf(wq[(size_t)orow * WP + oc]);
    } else {                           // wk^T
        int idx = (b - 768) * 256 + threadIdx.x;
        int oc = idx / 512;
        int orow = idx % 512;
        wqkT_bf[256 * 512 + idx] = f2bf(wk[(size_t)orow * WP + oc]);
    }
}

// ===== batched bf16 MFMA NT GEMM, 64x128 tile, BK=64 =====
// C[b,m,n] = sum_k A[b,m,k]*B[b,n,k]; 4 waves (2x2), wave = 32x64.
// epi: 0 none, 1 exp, 2 gated-final-blend, 3 exp + den row-sum atomic
__global__ __launch_bounds__(256) void gemm_mfma_ntb(
    const unsigned short* __restrict__ A, int lda, size_t sA,
    const unsigned short* __restrict__ B, int ldb, size_t sB,
    float* __restrict__ C, unsigned short* __restrict__ Cbf, int ldc, size_t sC,
    int K, const float* __restrict__ bias, const float* __restrict__ addsrc,
    const float* __restrict__ alphav, float* __restrict__ denv, int epi)
{
    __shared__ __align__(16) unsigned short As[64 * 64];
    __shared__ __align__(16) unsigned short Bs[128 * 64];
    const int tid = threadIdx.x;
    const int wave = tid >> 6, lane = tid & 63;
    const int l15 = lane & 15, l4 = lane >> 4;
    const int wm = wave >> 1, wn = wave & 1;
    const size_t bm = (size_t)blockIdx.x * 64;
    const size_t bn = (size_t)blockIdx.y * 128;
    const int z = blockIdx.z;
    const unsigned short* Ab = A + (size_t)z * sA;
    const unsigned short* Bb = B + (size_t)z * sB;
    const int swzr = (l15 & 7) << 3;
    f32x4 acc[2][4] = {};
    for (int k0 = 0; k0 < K; k0 += 64) {
        __syncthreads();
#pragma unroll
        for (int c2 = 0; c2 < 2; ++c2) {       // A: 64x64 = 512 x 16B
            int id = c2 * 256 + tid;
            int row = id >> 3;
            int cg = ((id & 7) ^ (row & 7)) << 3;
            gload_lds16(Ab + (bm + row) * (size_t)lda + k0 + cg, As + id * 8);
        }
#pragma unroll
        for (int c2 = 0; c2 < 4; ++c2) {       // B: 128x64 = 1024 x 16B
            int id = c2 * 256 + tid;
            int row = id >> 3;
            int cg = ((id & 7) ^ (row & 7)) << 3;
            gload_lds16(Bb + (bn + row) * (size_t)ldb + k0 + cg, Bs + id * 8);
        }
        __syncthreads();
#pragma unroll
        for (int c = 0; c < 2; ++c) {
            bf16x8 af[2], bfv[4];
#pragma unroll
            for (int i = 0; i < 2; ++i)
                af[i] = *reinterpret_cast<const bf16x8*>(
                    &As[(wm * 32 + i * 16 + l15) * 64 + ((c * 32 + l4 * 8) ^ swzr)]);
#pragma unroll
            for (int j = 0; j < 4; ++j)
                bfv[j] = *reinterpret_cast<const bf16x8*>(
                    &Bs[(wn * 64 + j * 16 + l15) * 64 + ((c * 32 + l4 * 8) ^ swzr)]);
#pragma unroll
            for (int i = 0; i < 2; ++i)
#pragma unroll
                for (int j = 0; j < 4; ++j)
                    acc[i][j] = __builtin_amdgcn_mfma_f32_16x16x32_bf16(
                        af[i], bfv[j], acc[i][j], 0, 0, 0);
        }
    }
    float* Cz = C ? C + (size_t)z * sC : nullptr;
    unsigned short* Cbz = Cbf ? Cbf + (size_t)z * sC : nullptr;
    if (epi == 3) {
        // exp + bf16 store + per-row denominator accumulation
#pragma unroll
        for (int i = 0; i < 2; ++i)
#pragma unroll
            for (int r = 0; r < 4; ++r) {
                size_t row = bm + wm * 32 + i * 16 + l4 * 4 + r;
                float s = 0.f;
#pragma unroll
                for (int j = 0; j < 4; ++j) {
                    size_t col = bn + wn * 64 + j * 16 + l15;
                    float e = __expf(acc[i][j][r]);
                    s += e;
                    Cbz[row * (size_t)ldc + col] = f2bf(e);
                }
                s += __shfl_xor(s, 1); s += __shfl_xor(s, 2);
                s += __shfl_xor(s, 4); s += __shfl_xor(s, 8);
                if (l15 == 0) atomicAdd(denv + (size_t)z * MLM + row, s);
            }
        return;
    }
#pragma unroll
    for (int i = 0; i < 2; ++i)
#pragma unroll
        for (int j = 0; j < 4; ++j)
#pragma unroll
            for (int r = 0; r < 4; ++r) {
                size_t row = bm + wm * 32 + i * 16 + l4 * 4 + r;
                size_t col = bn + wn * 64 + j * 16 + l15;
                float v = acc[i][j][r];
                if (bias) v += bias[col];
                if (epi == 2) {
                    float xl = alphav[row] * v;
                    float w = 1.f / (1.f + __expf(xl));
                    float sq = w * w;
                    v = xl * 2.f * sq + 2.f * addsrc[row * (size_t)ldc + col] * (1.f - sq);
                    Cz[row * (size_t)ldc + col] = v;
                } else {
                    if (addsrc) v += addsrc[row * (size_t)ldc + col];
                    if (epi == 1) v = __expf(v);
                    if (Cz)  Cz[row * (size_t)ldc + col] = v;
                    if (Cbz) Cbz[row * (size_t)ldc + col] = f2bf(v);
                }
            }
}

// ===== bf16 NT GEMM for pinv: C = beta*(A@B) + alpha*A =====
__global__ __launch_bounds__(256) void bmm_h(
    const unsigned short* __restrict__ Ah, const unsigned short* __restrict__ Bh,
    unsigned short* __restrict__ Crh, unsigned short* __restrict__ Cth,
    int M, int N, int K, int ntn, float alpha, float beta)
{
    __shared__ __align__(16) unsigned short LAh[64 * 64];
    __shared__ __align__(16) unsigned short LBh[64 * 64];
    const int tid = threadIdx.x;
    const int wave = tid >> 6, lane = tid & 63;
    const int l15 = lane & 15, l4 = lane >> 4;
    const int wm = wave >> 1, wn = wave & 1;
    const int b = blockIdx.y;
    const int tm = blockIdx.x / ntn, tn = blockIdx.x % ntn;
    const unsigned short* Ahb = Ah + (size_t)b * M * K;
    const unsigned short* Bhb = Bh + (size_t)b * N * K;
    const int swzr = (l15 & 7) << 3;
    f32x4 acc[2][2] = {};
    for (int k0 = 0; k0 < K; k0 += 64) {
        __syncthreads();
#pragma unroll
        for (int c2 = 0; c2 < 2; ++c2) {
            int id = c2 * 256 + tid;
            int row = id >> 3;
            int cg = ((id & 7) ^ (row & 7)) << 3;
            gload_lds16(Ahb + (size_t)(tm * 64 + row) * K + k0 + cg, LAh + id * 8);
            gload_lds16(Bhb + (size_t)(tn * 64 + row) * K + k0 + cg, LBh + id * 8);
        }
        __syncthreads();
#pragma unroll
        for (int c = 0; c < 2; ++c) {
            bf16x8 ah[2], bh[2];
#pragma unroll
            for (int i = 0; i < 2; ++i)
                ah[i] = *reinterpret_cast<const bf16x8*>(
                    &LAh[(wm * 32 + i * 16 + l15) * 64 + ((c * 32 + l4 * 8) ^ swzr)]);
#pragma unroll
            for (int j = 0; j < 2; ++j)
                bh[j] = *reinterpret_cast<const bf16x8*>(
                    &LBh[(wn * 32 + j * 16 + l15) * 64 + ((c * 32 + l4 * 8) ^ swzr)]);
#pragma unroll
            for (int i = 0; i < 2; ++i)
#pragma unroll
                for (int j = 0; j < 2; ++j)
                    acc[i][j] = __builtin_amdgcn_mfma_f32_16x16x32_bf16(ah[i], bh[j], acc[i][j], 0, 0, 0);
        }
    }
    unsigned short* Crhb = Crh ? Crh + (size_t)b * M * N : nullptr;
    unsigned short* Cthb = Cth ? Cth + (size_t)b * M * N : nullptr;
#pragma unroll
    for (int i = 0; i < 2; ++i)
#pragma unroll
        for (int j = 0; j < 2; ++j)
#pragma unroll
            for (int r = 0; r < 4; ++r) {
                int row = tm * 64 + wm * 32 + i * 16 + l4 * 4 + r;
                int col = tn * 64 + wn * 32 + j * 16 + l15;
                float v = beta * acc[i][j][r];
                if (alpha != 0.f)
                    v += alpha * bf2f(Ahb[(size_t)row * K + col]);   // square (M==K) only
                unsigned short hi = f2bf(v);
                if (Crhb) Crhb[(size_t)row * N + col] = hi;
                if (Cthb) Cthb[(size_t)col * M + row] = hi;
            }
}

// ===== pv3: partials[kc][h][i][d] = sum_{j in chunk} P[h,i,j]*vT[h,d,j] =====
__global__ __launch_bounds__(256) void pv3_mfma(
    const unsigned short* __restrict__ sc, const unsigned short* __restrict__ vT,
    float* __restrict__ part)
{
    __shared__ __align__(16) unsigned short As[64 * 64];
    __shared__ __align__(16) unsigned short Bs[64 * 64];
    const int tid = threadIdx.x;
    const int wave = tid >> 6, lane = tid & 63;
    const int l15 = lane & 15, l4 = lane >> 4;
    const int wm = wave >> 1, wn = wave & 1;
    const int it = blockIdx.x, kc = blockIdx.y, h = blockIdx.z;
    const unsigned short* Ap = sc + (size_t)h * MLM * NSEQ + (size_t)(it * 64) * NSEQ + kc * 512;
    const unsigned short* Bp = vT + (size_t)h * DH * NSEQ + kc * 512;
    const int swzr = (l15 & 7) << 3;
    f32x4 acc[2][2] = {};
    for (int k0 = 0; k0 < 512; k0 += 64) {
        __syncthreads();
#pragma unroll
        for (int c2 = 0; c2 < 2; ++c2) {
            int id = c2 * 256 + tid;
            int row = id >> 3;
            int cg = ((id & 7) ^ (row & 7)) << 3;
            gload_lds16(Ap + (size_t)row * NSEQ + k0 + cg, As + id * 8);
        }
#pragma unroll
        for (int c2 = 0; c2 < 2; ++c2) {
            int id = c2 * 256 + tid;
            int row = id >> 3;
            int cg = ((id & 7) ^ (row & 7)) << 3;
            gload_lds16(Bp + (size_t)row * NSEQ + k0 + cg, Bs + id * 8);
        }
        __syncthreads();
#pragma unroll
        for (int ks = 0; ks < 2; ++ks) {
            bf16x8 af[2], bfv[2];
#pragma unroll
            for (int i = 0; i < 2; ++i)
                af[i] = *reinterpret_cast<const bf16x8*>(
                    &As[(wm * 32 + i * 16 + l15) * 64 + ((ks * 32 + l4 * 8) ^ swzr)]);
#pragma unroll
            for (int j = 0; j < 2; ++j)
                bfv[j] = *reinterpret_cast<const bf16x8*>(
                    &Bs[(wn * 32 + j * 16 + l15) * 64 + ((ks * 32 + l4 * 8) ^ swzr)]);
#pragma unroll
            for (int i = 0; i < 2; ++i)
#pragma unroll
                for (int j = 0; j < 2; ++j)
                    acc[i][j] = __builtin_amdgcn_mfma_f32_16x16x32_bf16(af[i], bfv[j], acc[i][j], 0, 0, 0);
        }
    }
    float* Cp = part + ((size_t)(kc * 8 + h) * MLM + it * 64) * DH;
#pragma unroll
    for (int i = 0; i < 2; ++i)
#pragma unroll
        for (int j = 0; j < 2; ++j)
#pragma unroll
            for (int r = 0; r < 4; ++r)
                Cp[(wm * 32 + i * 16 + l4 * 4 + r) * DH + wn * 32 + j * 16 + l15] = acc[i][j][r];
}

// ===== fused a1 (round-10 proven): QK + exp-softmax + PV + conv -> bf16 attn =====
// LDS: A(8KB) overlapped by P(32KB) overlapped by att(16KB)+vbuf(12KB); kls/bbT from L2.
__global__ __launch_bounds__(256) void a1_fused(
    const unsigned short* __restrict__ qkvbf,
    const unsigned short* __restrict__ kls,     // [h][256][64] (k_l * 0.125)
    const unsigned short* __restrict__ bbT,     // [h][64][256]
    const float* __restrict__ kern,
    unsigned short* __restrict__ attnbf)
{
    __shared__ __align__(16) unsigned short lds[16384];  // 32 KB
    __shared__ float den[2][64];
    __shared__ float kc_s[KCONV];
    const int tid = threadIdx.x;
    const int wave = tid >> 6, lane = tid & 63;
    const int l15 = lane & 15, l4 = lane >> 4;
    const int wm = wave >> 1, wn = wave & 1;
    const int n0 = blockIdx.x * 64;
    const int h = blockIdx.y;
    const int swzr = (l15 & 7) << 3;

    if (tid < KCONV) kc_s[tid] = kern[h * KCONV + tid];
    // stage A (q rows 64x64) only; kls fragments come straight from L2
#pragma unroll
    for (int c2 = 0; c2 < 2; ++c2) {
        int id = c2 * 256 + tid;
        int row = id >> 3, cg = ((id & 7) ^ (row & 7)) << 3;
        gload_lds16(qkvbf + (size_t)(n0 + row) * QKV_LD + h * DH + cg, lds + id * 8);
    }
    __syncthreads();
    // QK: S = q . kls^T  (64 x 256), wave tile 32 x 128
    const unsigned short* klsh = kls + (size_t)h * (MLM * DH);
    f32x4 acc[2][8] = {};
#pragma unroll
    for (int c = 0; c < 2; ++c) {
        bf16x8 af[2], bv[8];
#pragma unroll
        for (int i = 0; i < 2; ++i) {
            int row = wm * 32 + i * 16 + l15;
            af[i] = *reinterpret_cast<const bf16x8*>(&lds[row * 64 + ((c * 32 + l4 * 8) ^ swzr)]);
        }
#pragma unroll
        for (int j = 0; j < 8; ++j) {
            int brow = wn * 128 + j * 16 + l15;
            bv[j] = *reinterpret_cast<const bf16x8*>(&klsh[brow * 64 + c * 32 + l4 * 8]);
        }
#pragma unroll
        for (int i = 0; i < 2; ++i)
#pragma unroll
            for (int j = 0; j < 8; ++j)
                acc[i][j] = __builtin_amdgcn_mfma_f32_16x16x32_bf16(af[i], bv[j], acc[i][j], 0, 0, 0);
    }
    __syncthreads();   // all A reads complete -> P may overlay
    // exp (scores tiny: no max), row sums, write P bf16 swizzled at lds[0]
    float rs[2][4] = {};
#pragma unroll
    for (int i = 0; i < 2; ++i)
#pragma unroll
        for (int j = 0; j < 8; ++j)
#pragma unroll
            for (int r = 0; r < 4; ++r) {
                float e = __expf(acc[i][j][r]);
                rs[i][r] += e;
                int row = wm * 32 + i * 16 + l4 * 4 + r;
                int col = wn * 128 + j * 16 + l15;
                lds[row * 256 + (col ^ ((row & 7) << 3))] = f2bf(e);
            }
#pragma unroll
    for (int i = 0; i < 2; ++i)
#pragma unroll
        for (int r = 0; r < 4; ++r) {
            float s = rs[i][r];
            s += __shfl_xor(s, 1); s += __shfl_xor(s, 2);
            s += __shfl_xor(s, 4); s += __shfl_xor(s, 8);
            if (l15 == 0) den[wn][wm * 32 + i * 16 + l4 * 4 + r] = s;
        }
    __syncthreads();
    // PV: out = P @ bb  (64 x 64), wave tile 32 x 32; B frags from L2
    f32x4 acc2[2][2] = {};
    const unsigned short* bbh = bbT + (size_t)h * DH * MLM;
#pragma unroll
    for (int k0 = 0; k0 < 256; k0 += 32) {
        bf16x8 af2[2], bv2[2];
#pragma unroll
        for (int i = 0; i < 2; ++i) {
            int row = wm * 32 + i * 16 + l15;
            af2[i] = *reinterpret_cast<const bf16x8*>(
                &lds[row * 256 + ((k0 + l4 * 8) ^ ((row & 7) << 3))]);
        }
#pragma unroll
        for (int j = 0; j < 2; ++j) {
            int d = wn * 32 + j * 16 + l15;
            bv2[j] = *reinterpret_cast<const bf16x8*>(&bbh[d * MLM + k0 + l4 * 8]);
        }
#pragma unroll
        for (int i = 0; i < 2; ++i)
#pragma unroll
            for (int j = 0; j < 2; ++j)
                acc2[i][j] = __builtin_amdgcn_mfma_f32_16x16x32_bf16(af2[i], bv2[j], acc2[i][j], 0, 0, 0);
    }
    __syncthreads();   // P reads done; reuse LDS
    // normalized PV -> LDS fp32 att[64][64] at lds[0]; v window 96x64 at lds[8192]
    float* att = reinterpret_cast<float*>(lds);              // 16 KB
    unsigned short* vbuf = &lds[8192];                       // 12 KB
#pragma unroll
    for (int i = 0; i < 2; ++i)
#pragma unroll
        for (int r = 0; r < 4; ++r) {
            int row = wm * 32 + i * 16 + l4 * 4 + r;
            float inv = 1.f / (den[0][row] + den[1][row]);
#pragma unroll
            for (int j = 0; j < 2; ++j)
                att[row * 64 + wn * 32 + j * 16 + l15] = acc2[i][j][r] * inv;
        }
#pragma unroll
    for (int s = 0; s < 6; ++s) {
        int id = s * 256 + tid;
        int r = id >> 4, c4 = (id & 15) * 4;
        int n = n0 - 16 + r;
        ushort4 u = {0, 0, 0, 0};
        if (n >= 0 && n < NSEQ)
            u = *reinterpret_cast<const ushort4*>(qkvbf + (size_t)n * QKV_LD + 1024 + h * 64 + c4);
        *reinterpret_cast<ushort4*>(vbuf + r * 64 + c4) = u;
    }
    __syncthreads();
    // conv: each thread owns 16 rows of one column
    const int col = tid & 63, rowg = tid >> 6;
    float vwin[48];
#pragma unroll
    for (int t = 0; t < 48; ++t) vwin[t] = bf2f(vbuf[(rowg * 16 + t) * 64 + col]);
#pragma unroll
    for (int rr = 0; rr < 16; ++rr) {
        float cv = 0.f;
#pragma unroll
        for (int t = 0; t < KCONV; ++t) cv += kc_s[t] * vwin[rr + t];
        int row = rowg * 16 + rr;
        attnbf[(size_t)(n0 + row) * INNER + h * DH + col] = f2bf(att[row * 64 + col] + cv);
    }
}

// ------------- landmark means from bf16 qkv (+ bf16 copies) -------------
__global__ __launch_bounds__(64) void landmark2_k(
    const unsigned short* __restrict__ qkvbf, float* __restrict__ q_l, float* __restrict__ k_l,
    unsigned short* __restrict__ ql_bf, unsigned short* __restrict__ kls_bf)
{
    int m = blockIdx.x, h = blockIdx.y, d = threadIdx.x;
    float sq = 0.f, sk = 0.f;
    for (int i = 0; i < LSUB; ++i) {
        size_t n = (size_t)m * LSUB + i;
        sq += bf2f(qkvbf[n * QKV_LD + h * DH + d]);
        sk += bf2f(qkvbf[n * QKV_LD + 512 + h * DH + d]);
    }
    float qv = sq * (0.125f / (float)LSUB);
    float kv = sk * (1.f / (float)LSUB);
    size_t o = ((size_t)h * MLM + m) * DH + d;
    q_l[o] = qv; k_l[o] = kv;
    ql_bf[o] = f2bf(qv);
    kls_bf[o] = f2bf(kv * 0.125f);
}

// ------------- v transpose: vT[h][d][n] = qkv_bf[n][1024+h*64+d] -------------
__global__ __launch_bounds__(256) void vt_k(
    const unsigned short* __restrict__ qkvbf, unsigned short* __restrict__ vT)
{
    __shared__ unsigned short tile[128][72];
    const int t = threadIdx.x;
    const int n0 = blockIdx.x * 128;
    const int h = blockIdx.y;
#pragma unroll
    for (int s = 0; s < 4; ++s) {
        int cid = s * 256 + t;
        int row = cid >> 3, ch = (cid & 7) * 8;
        uint4 v = *reinterpret_cast<const uint4*>(
            qkvbf + (size_t)(n0 + row) * QKV_LD + 1024 + h * 64 + ch);
        *reinterpret_cast<uint4*>(&tile[row][ch]) = v;
    }
    __syncthreads();
#pragma unroll
    for (int s = 0; s < 4; ++s) {
        int cid = s * 256 + t;
        int d = cid >> 4, nch = (cid & 15) * 8;
        unsigned short o[8];
#pragma unroll
        for (int i = 0; i < 8; ++i) o[i] = tile[nch + i][d];
        *reinterpret_cast<uint4*>(vT + (size_t)h * DH * NSEQ + (size_t)d * NSEQ + n0 + nch) =
            *reinterpret_cast<uint4*>(o);
    }
}

// ------------- a2 = softmax(q_l @ k_l^T) rows -------------
__global__ __launch_bounds__(256) void a2_k(
    const float* __restrict__ q_l, const float* __restrict__ k_l, float* __restrict__ a2)
{
    int i = blockIdx.x, h = blockIdx.y, t = threadIdx.x;
    __shared__ float ql[64];
    __shared__ float red[256];
    if (t < 64) ql[t] = q_l[((size_t)h * MLM + i) * DH + t];
    __syncthreads();
    const float* kr = k_l + ((size_t)h * MLM + t) * DH;
    float s = 0.f;
#pragma unroll
    for (int d = 0; d < 64; d += 4) {
        float4 kv = *reinterpret_cast<const float4*>(kr + d);
        s += kv.x * ql[d] + kv.y * ql[d + 1] + kv.z * ql[d + 2] + kv.w * ql[d + 3];
    }
    red[t] = s; __syncthreads();
    for (int off = 128; off > 0; off >>= 1) { if (t < off) red[t] = fmaxf(red[t], red[t + off]); __syncthreads(); }
    float m = red[0]; __syncthreads();
    float e = __expf(s - m);
    red[t] = e; __syncthreads();
    for (int off = 128; off > 0; off >>= 1) { if (t < off) red[t] += red[t + off]; __syncthreads(); }
    a2[(((size_t)h * MLM + i) * MLM) + t] = e / red[0];
}

// ------------- global max of row/col abs-sums of a2 -------------
__global__ __launch_bounds__(256) void absmax_k(
    const float* __restrict__ a2, unsigned int* __restrict__ scal)
{
    int b = blockIdx.x, t = threadIdx.x;
    __shared__ float red[256];
    float sum = 0.f;
    if (b < 8) {
        const float* r = a2 + ((size_t)b * MLM + t) * MLM;
        for (int j = 0; j < MLM; ++j) sum += fabsf(r[j]);
    } else {
        int h = b - 8;
        for (int i = 0; i < MLM; ++i) sum += fabsf(a2[((size_t)h * MLM + i) * MLM + t]);
    }
    red[t] = sum; __syncthreads();
    for (int off = 128; off > 0; off >>= 1) { if (t < off) red[t] = fmaxf(red[t], red[t + off]); __syncthreads(); }
    if (t == 0) atomicMax(scal + (b < 8 ? 0 : 1), __float_as_uint(red[0]));
}

// ------------- zinit2: a2 + z0 (row & T) to bf16 -------------
__global__ __launch_bounds__(256) void zinit2_k(
    const float* __restrict__ a2, const unsigned int* __restrict__ scal,
    unsigned short* __restrict__ a2h,
    unsigned short* __restrict__ zrh, unsigned short* __restrict__ zth)
{
    int idx = blockIdx.x * 256 + threadIdx.x;
    float inv = 1.f / (__uint_as_float(scal[0]) * __uint_as_float(scal[1]));
    int h = idx >> 16, rem = idx & 65535, i = rem >> 8, j = rem & 255;
    float aij = a2[idx];
    a2h[idx] = f2bf(aij);
    zth[idx] = f2bf(aij * inv);                              // z0T[i][j] = a2[i][j]*inv
    zrh[idx] = f2bf(a2[((size_t)h << 16) + (j << 8) + i] * inv);  // z0row[i][j] = a2[j][i]*inv
}

// ------------- red3: sum partials, divide, write a3v^T bf16 -------------
__global__ __launch_bounds__(256) void red3_k(
    const float* __restrict__ part, const float* __restrict__ den3,
    unsigned short* __restrict__ a3vth)
{
    int o = blockIdx.x * 256 + threadIdx.x;   // [8][256][64]
    float s = 0.f;
#pragma unroll
    for (int kc = 0; kc < 16; ++kc) s += part[(size_t)kc * 131072 + o];
    s /= den3[o >> 6];
    int h = o >> 14, i = (o >> 6) & 255, d = o & 63;
    a3vth[(h << 14) + (d << 8) + i] = f2bf(s);
}

// ------------- sparse edge scores: 8 lanes/edge, 32 dims/lane -------------
__global__ __launch_bounds__(256) void edge2_k(
    const unsigned short* __restrict__ qke,
    const int* __restrict__ rows, const int* __restrict__ cols,
    const float* __restrict__ vals, float* __restrict__ A_raw)
{
    const int e = blockIdx.x * 32 + (threadIdx.x >> 3);
    const int g = threadIdx.x & 7;
    const int r = rows[e], c = cols[e];
    const unsigned short* qr = qke + (size_t)r * 512 + g * 32;
    const unsigned short* kr = qke + (size_t)c * 512 + 256 + g * 32;
    float s = 0.f;
#pragma unroll
    for (int u = 0; u < 4; ++u) {
        uint4 qa = *reinterpret_cast<const uint4*>(qr + u * 8);
        uint4 ka = *reinterpret_cast<const uint4*>(kr + u * 8);
        unsigned int qw[4] = {qa.x, qa.y, qa.z, qa.w};
        unsigned int kw[4] = {ka.x, ka.y, ka.z, ka.w};
#pragma unroll
        for (int q = 0; q < 4; ++q) {
            s += bf2f((unsigned short)(qw[q] & 0xFFFF)) * bf2f((unsigned short)(kw[q] & 0xFFFF));
            s += bf2f((unsigned short)(qw[q] >> 16)) * bf2f((unsigned short)(kw[q] >> 16));
        }
    }
    s += __shfl_xor(s, 1); s += __shfl_xor(s, 2); s += __shfl_xor(s, 4);
    if (g == 0) atomicAdd(&A_raw[r], s * vals[e] * 0.0625f);
}

// ------------- alpha = softmax(A_raw) -------------
__global__ __launch_bounds__(1024) void alpha_k(
    const float* __restrict__ A_raw, float* __restrict__ alpha)
{
    __shared__ float red[1024];
    int t = threadIdx.x;
    float m = -1e30f;
    for (int i = t; i < NSEQ; i += 1024) m = fmaxf(m, A_raw[i]);
    red[t] = m; __syncthreads();
    for (int off = 512; off > 0; off >>= 1) { if (t < off) red[t] = fmaxf(red[t], red[t + off]); __syncthreads(); }
    m = red[0]; __syncthreads();
    float s = 0.f;
    for (int i = t; i < NSEQ; i += 1024) s += __expf(A_raw[i] - m);
    red[t] = s; __syncthreads();
    for (int off = 512; off > 0; off >>= 1) { if (t < off) red[t] += red[t + off]; __syncthreads(); }
    float inv = 1.f / red[0];
    for (int i = t; i < NSEQ; i += 1024) alpha[i] = __expf(A_raw[i] - m) * inv;
}

extern "C" void kernel_launch(void* const* d_in, const int* in_sizes, int n_in,
                              void* d_out, int out_size, void* d_ws, size_t ws_size,
                              hipStream_t stream)
{
    const float* dense      = (const float*)d_in[0];
    const int*   adj_rows   = (const int*)d_in[1];
    const int*   adj_cols   = (const int*)d_in[2];
    const float* adj_vals   = (const float*)d_in[3];
    const float* wq         = (const float*)d_in[4];
    const float* wk         = (const float*)d_in[5];
    const float* w_qkv      = (const float*)d_in[6];
    const float* w_out      = (const float*)d_in[7];
    const float* b_out      = (const float*)d_in[8];
    const float* res_kernel = (const float*)d_in[9];
    const float* wv_w       = (const float*)d_in[10];
    const float* wv_b       = (const float*)d_in[11];
    const int E = in_sizes[1];

    float* ws  = (float*)d_ws;
    float* out = (float*)d_out;
    float* A_raw = out + (size_t)NSEQ * DDIM;

    unsigned short* qkv_bf   = (unsigned short*)(ws + OFF_QKVBF);
    unsigned short* vT       = (unsigned short*)(ws + OFF_VT);
    unsigned short* sc       = (unsigned short*)(ws + OFF_SC);
    unsigned short* attn_bf  = (unsigned short*)(ws + OFF_ATTNBF);
    unsigned short* qke_bf   = (unsigned short*)(ws + OFF_QKE);
    unsigned short* dense_bf = (unsigned short*)(ws + OFF_DENSEBF);
    unsigned short* wqkv_bf  = (unsigned short*)(ws + OFF_WQKVBF);
    unsigned short* wout_bf  = (unsigned short*)(ws + OFF_WOUTBF);
    unsigned short* wqkT_bf  = (unsigned short*)(ws + OFF_WQKT);
    unsigned short* wv_bf    = (unsigned short*)(ws + OFF_WVBF);
    unsigned short* ql_bf    = (unsigned short*)(ws + OFF_QLBF);
    unsigned short* kls_bf   = (unsigned short*)(ws + OFF_KLSBF);
    unsigned short* bbT_bf   = (unsigned short*)(ws + OFF_BBT);
    unsigned short* enc_bf   = (unsigned short*)(ws + OFF_ENCBF);

#define U16(off) ((unsigned short*)(ws + (off)))

    (void)hipMemsetAsync(A_raw, 0, NSEQ * sizeof(float), stream);
    (void)hipMemsetAsync(ws + OFF_SCAL, 0, 2 * sizeof(unsigned int), stream);
    (void)hipMemsetAsync(ws + OFF_DEN3, 0, HEADS * MLM * sizeof(float), stream);

    // ---- input conversions ----
    cvt_bf16_k<<<(NSEQ * DDIM) / 2048, 256, 0, stream>>>(dense, dense_bf);
    cvt_bf16_k<<<(1536 * DDIM) / 2048, 256, 0, stream>>>(w_qkv, wqkv_bf);

    // qkv = dense @ w_qkv^T  -> bf16
    gemm_mfma_ntb<<<dim3(NSEQ / 64, 1536 / 128, 1), 256, 0, stream>>>(
        dense_bf, DDIM, 0, wqkv_bf, DDIM, 0, nullptr, qkv_bf, QKV_LD, 0,
        DDIM, nullptr, nullptr, nullptr, nullptr, 0);

    landmark2_k<<<dim3(MLM, HEADS), 64, 0, stream>>>(
        qkv_bf, ws + OFF_QL, ws + OFF_KL, ql_bf, kls_bf);
    vt_k<<<dim3(NSEQ / 128, HEADS), 256, 0, stream>>>(qkv_bf, vT);

    // ---- a3 pipeline (exp-scores + fused den accumulation) ----
    gemm_mfma_ntb<<<dim3(MLM / 64, NSEQ / 128, HEADS), 256, 0, stream>>>(
        ql_bf, DH, (size_t)MLM * DH, qkv_bf + 512, QKV_LD, DH,
        nullptr, sc, NSEQ, (size_t)MLM * NSEQ, DH, nullptr, nullptr, nullptr,
        ws + OFF_DEN3, 3);
    pv3_mfma<<<dim3(4, 16, HEADS), 256, 0, stream>>>(sc, vT, ws + OFF_PART);
    red3_k<<<512, 256, 0, stream>>>(ws + OFF_PART, ws + OFF_DEN3, U16(A3VT_H));

    a2_k<<<dim3(MLM, HEADS), 256, 0, stream>>>(ws + OFF_QL, ws + OFF_KL, ws + A2F32);
    absmax_k<<<16, 256, 0, stream>>>(ws + A2F32, (unsigned int*)(ws + OFF_SCAL));
    zinit2_k<<<(HEADS * MLM * MLM) / 256, 256, 0, stream>>>(
        ws + A2F32, (const unsigned int*)(ws + OFF_SCAL),
        U16(A2R_H), U16(Z0R_H), U16(Z0T_H));

    // pinv iterations (bf16 MFMA; Newton-Schulz is self-correcting)
    for (int it = 0; it < 6; ++it) {
        size_t zr_h = (it & 1) ? Z1R_H : Z0R_H;
        size_t zt_h = (it & 1) ? Z1T_H : Z0T_H;
        size_t or_h = (it & 1) ? Z0R_H : Z1R_H;
        size_t ot_h = (it & 1) ? Z0T_H : Z1T_H;
        bmm_h<<<dim3(16, HEADS), 256, 0, stream>>>(
            U16(A2R_H), U16(zt_h), U16(PR_H), U16(PT_H), 256, 256, 256, 4, 0.f, 1.f);
        bmm_h<<<dim3(16, HEADS), 256, 0, stream>>>(
            U16(PR_H), U16(PT_H), nullptr, U16(T1T_H), 256, 256, 256, 4, 7.f, -1.f);
        bmm_h<<<dim3(16, HEADS), 256, 0, stream>>>(
            U16(PR_H), U16(T1T_H), nullptr, U16(T2T_H), 256, 256, 256, 4, 15.f, -1.f);
        bmm_h<<<dim3(16, HEADS), 256, 0, stream>>>(
            U16(zr_h), U16(T2T_H), U16(or_h), U16(ot_h), 256, 256, 256, 4, 3.25f, -0.25f);
    }
    // bbT = (z @ a3v)^T = NT(a3vT, z_row)   [64 x 256]
    bmm_h<<<dim3(4, HEADS), 256, 0, stream>>>(
        U16(A3VT_H), U16(Z0R_H), bbT_bf, nullptr, 64, 256, 256, 4, 0.f, 1.f);

    // ---- fused a1 (QK + exp-softmax + PV + conv -> bf16 attn) ----
    a1_fused<<<dim3(NSEQ / 64, HEADS), 256, 0, stream>>>(
        qkv_bf, kls_bf, bbT_bf, res_kernel, attn_bf);

    // ---- late weights to bf16 (single merged launch) ----
    wcvt_k<<<1280, 256, 0, stream>>>(w_out, wout_bf, wv_w, wv_bf, wq, wk, wqkT_bf);

    // enc = attn @ w_out^T + b_out + dense  (fp32 + bf16)
    gemm_mfma_ntb<<<dim3(NSEQ / 64, DDIM / 128, 1), 256, 0, stream>>>(
        attn_bf, INNER, 0, wout_bf, INNER, 0, ws + OFF_ENC, enc_bf, DDIM, 0,
        INNER, b_out, dense, nullptr, nullptr, 0);

    // qke = enc @ [wq|wk] -> bf16
    gemm_mfma_ntb<<<dim3(NSEQ / 64, 512 / 128, 1), 256, 0, stream>>>(
        enc_bf, DDIM, 0, wqkT_bf, DDIM, 0, nullptr, qke_bf, 512, 0,
        DDIM, nullptr, nullptr, nullptr, nullptr, 0);

    edge2_k<<<E / 32, 256, 0, stream>>>(qke_bf, adj_rows, adj_cols, adj_vals, A_raw);
    alpha_k<<<1, 1024, 0, stream>>>(A_raw, ws + OFF_ALPHA);

    // out = gated_blend(alpha, dense @ wv^T + wv_b, enc)  -- fused final
    gemm_mfma_ntb<<<dim3(NSEQ / 64, DDIM / 128, 1), 256, 0, stream>>>(
        dense_bf, DDIM, 0, wv_bf, DDIM, 0, out, nullptr, DDIM, 0,
        DDIM, wv_b, ws + OFF_ENC, ws + OFF_ALPHA, nullptr, 2);
}

// Round 14
// 473.753 us; speedup vs baseline: 3.5163x; 1.0498x over previous
//
#include <hip/hip_runtime.h>
#include <hip/hip_bf16.h>

// Problem constants (fixed by reference)
#define NSEQ 8192
#define DDIM 512
#define HEADS 8
#define DH 64
#define MLM 256
#define LSUB 32          // NSEQ / MLM
#define WP 256
#define KCONV 33
#define INNER 512        // HEADS*DH
#define QKV_LD 1536

// ---------------- workspace layout (float offsets) ----------------
static const size_t OFF_QKVBF  = 0;          // bf16 8192*1536 = 6,291,456 fl
static const size_t OFF_VT     = 6291456;    // bf16 8*64*8192 = 2,097,152 fl
static const size_t OFF_SC     = 8388608;    // bf16 exp-scores 8*256*8192 (ends 16,777,216)
// pinv overlays inside SC (alive only after scores consumed):
#define PS (8388608)
static const size_t A2R_H = PS + 0;        // each square buf: 262,144 fl (8*256*256 bf16)
static const size_t Z0R_H = PS + 524288;
static const size_t Z0T_H = PS + 1048576;
static const size_t Z1R_H = PS + 1572864;
static const size_t Z1T_H = PS + 2097152;
static const size_t PR_H  = PS + 2621440;
static const size_t PT_H  = PS + 3145728;
static const size_t T1T_H = PS + 3670016;
static const size_t T2T_H = PS + 4194304;
static const size_t A3VT_H= PS + 4718592;  // 65,536 fl
static const size_t A2F32 = PS + 4849664;  // fp32 8*256*256 = 524,288 fl
// after SC:
static const size_t OFF_ATTNBF = 16777216;   // bf16 8192*512 = 2,097,152 fl
static const size_t OFF_PART   = 18874368;   // fp32 pv3 partials 16*8*256*64 = 2,097,152 fl
// enc overlays dead qkv_bf region:
static const size_t OFF_ENC    = 0;          // fp32 8192*512 = 4,194,304 fl
static const size_t OFF_ENCBF  = 4194304;    // bf16 8192*512 = 2,097,152 fl
static const size_t OFF_QKE    = 6291456;    // bf16 8192*512 (vT dead)
// tail region:
static const size_t OFF_DENSEBF= 20971520;   // bf16 8192*512
static const size_t OFF_WQKVBF = 23068672;   // bf16 1536*512
static const size_t OFF_WOUTBF = 23461888;   // bf16 512*512
static const size_t OFF_WQKT   = 23592960;   // bf16 512*512 (wq^T | wk^T)
static const size_t OFF_WVBF   = 23724032;   // bf16 512*512
static const size_t OFF_QL     = 23855104;   // fp32 8*256*64
static const size_t OFF_KL     = 23986176;   // fp32 8*256*64
static const size_t OFF_QLBF   = 24117248;   // bf16 8*256*64
static const size_t OFF_KLSBF  = 24182784;   // bf16 8*256*64 (k_l * 0.125)
static const size_t OFF_BBT    = 24248320;   // bf16 8*64*256
static const size_t OFF_SCAL   = 24313856;   // 2 uints
static const size_t OFF_ALPHA  = 24313872;   // 8192 fp32
static const size_t OFF_DEN3   = 24322064;   // 2048 fp32

__device__ __forceinline__ float bf2f(unsigned short u) {
    return __uint_as_float(((unsigned int)u) << 16);
}
__device__ __forceinline__ unsigned short f2bf(float x) {
    unsigned int u = __float_as_uint(x);
    u += 0x7FFFu + ((u >> 16) & 1u);   // RNE
    return (unsigned short)(u >> 16);
}

typedef __attribute__((ext_vector_type(8))) short bf16x8;
typedef __attribute__((ext_vector_type(4))) float f32x4;

__device__ __forceinline__ void gload_lds16(const void* g, void* l) {
    __builtin_amdgcn_global_load_lds(
        (const __attribute__((address_space(1))) unsigned int*)g,
        (__attribute__((address_space(3))) unsigned int*)l, 16, 0, 0);
}

// ---------------- fp32 -> bf16 conversion (8 elems/thread) ----------------
__global__ __launch_bounds__(256) void cvt_bf16_k(
    const float* __restrict__ in, unsigned short* __restrict__ out)
{
    size_t i = ((size_t)blockIdx.x * 256 + threadIdx.x) * 8;
    float4 a = *reinterpret_cast<const float4*>(in + i);
    float4 b = *reinterpret_cast<const float4*>(in + i + 4);
    uint4 p;
    p.x = (unsigned int)f2bf(a.x) | ((unsigned int)f2bf(a.y) << 16);
    p.y = (unsigned int)f2bf(a.z) | ((unsigned int)f2bf(a.w) << 16);
    p.z = (unsigned int)f2bf(b.x) | ((unsigned int)f2bf(b.y) << 16);
    p.w = (unsigned int)f2bf(b.z) | ((unsigned int)f2bf(b.w) << 16);
    *reinterpret_cast<uint4*>(out + i) = p;
}

// ---- merged late-weight conversion: wout cvt | wv cvt | wq tcvt | wk tcvt ----
__global__ __launch_bounds__(256) void wcvt_k(
    const float* __restrict__ w_out, unsigned short* __restrict__ wout_bf,
    const float* __restrict__ wv_w,  unsigned short* __restrict__ wv_bf,
    const float* __restrict__ wq,    const float* __restrict__ wk,
    unsigned short* __restrict__ wqkT_bf)
{
    int b = blockIdx.x;
    if (b < 128) {                     // wout: 512*512, 8/thread
        size_t i = ((size_t)b * 256 + threadIdx.x) * 8;
        float4 a = *reinterpret_cast<const float4*>(w_out + i);
        float4 c = *reinterpret_cast<const float4*>(w_out + i + 4);
        uint4 p;
        p.x = (unsigned int)f2bf(a.x) | ((unsigned int)f2bf(a.y) << 16);
        p.y = (unsigned int)f2bf(a.z) | ((unsigned int)f2bf(a.w) << 16);
        p.z = (unsigned int)f2bf(c.x) | ((unsigned int)f2bf(c.y) << 16);
        p.w = (unsigned int)f2bf(c.z) | ((unsigned int)f2bf(c.w) << 16);
        *reinterpret_cast<uint4*>(wout_bf + i) = p;
    } else if (b < 256) {              // wv: 512*512, 8/thread
        size_t i = ((size_t)(b - 128) * 256 + threadIdx.x) * 8;
        float4 a = *reinterpret_cast<const float4*>(wv_w + i);
        float4 c = *reinterpret_cast<const float4*>(wv_w + i + 4);
        uint4 p;
        p.x = (unsigned int)f2bf(a.x) | ((unsigned int)f2bf(a.y) << 16);
        p.y = (unsigned int)f2bf(a.z) | ((unsigned int)f2bf(a.w) << 16);
        p.z = (unsigned int)f2bf(c.x) | ((unsigned int)f2bf(c.y) << 16);
        p.w = (unsigned int)f2bf(c.z) | ((unsigned int)f2bf(c.w) << 16);
        *reinterpret_cast<uint4*>(wv_bf + i) = p;
    } else if (b < 768) {              // wq^T: out[c][r]=wq[r][c], 256x512 out
        int idx = (b - 256) * 256 + threadIdx.x;
        int oc = idx / 512;
        int orow = idx % 512;
        wqkT_bf[idx] = f2bf(wq[(size_t)orow * WP + oc]);
    } else {                           // wk^T
        int idx = (b - 768) * 256 + threadIdx.x;
        int oc = idx / 512;
        int orow = idx % 512;
        wqkT_bf[256 * 512 + idx] = f2bf(wk[(size_t)orow * WP + oc]);
    }
}

// ===== batched bf16 MFMA NT GEMM, 64x128 tile, BK=64 =====
// C[b,m,n] = sum_k A[b,m,k]*B[b,n,k]; 4 waves (2x2), wave = 32x64.
// epi: 0 none, 1 exp, 2 gated-final-blend, 3 exp + den row-sum atomic
__global__ __launch_bounds__(256) void gemm_mfma_ntb(
    const unsigned short* __restrict__ A, int lda, size_t sA,
    const unsigned short* __restrict__ B, int ldb, size_t sB,
    float* __restrict__ C, unsigned short* __restrict__ Cbf, int ldc, size_t sC,
    int K, const float* __restrict__ bias, const float* __restrict__ addsrc,
    const float* __restrict__ alphav, float* __restrict__ denv, int epi)
{
    __shared__ __align__(16) unsigned short As[64 * 64];
    __shared__ __align__(16) unsigned short Bs[128 * 64];
    const int tid = threadIdx.x;
    const int wave = tid >> 6, lane = tid & 63;
    const int l15 = lane & 15, l4 = lane >> 4;
    const int wm = wave >> 1, wn = wave & 1;
    const size_t bm = (size_t)blockIdx.x * 64;
    const size_t bn = (size_t)blockIdx.y * 128;
    const int z = blockIdx.z;
    const unsigned short* Ab = A + (size_t)z * sA;
    const unsigned short* Bb = B + (size_t)z * sB;
    const int swzr = (l15 & 7) << 3;
    f32x4 acc[2][4] = {};
    for (int k0 = 0; k0 < K; k0 += 64) {
        __syncthreads();
#pragma unroll
        for (int c2 = 0; c2 < 2; ++c2) {       // A: 64x64 = 512 x 16B
            int id = c2 * 256 + tid;
            int row = id >> 3;
            int cg = ((id & 7) ^ (row & 7)) << 3;
            gload_lds16(Ab + (bm + row) * (size_t)lda + k0 + cg, As + id * 8);
        }
#pragma unroll
        for (int c2 = 0; c2 < 4; ++c2) {       // B: 128x64 = 1024 x 16B
            int id = c2 * 256 + tid;
            int row = id >> 3;
            int cg = ((id & 7) ^ (row & 7)) << 3;
            gload_lds16(Bb + (bn + row) * (size_t)ldb + k0 + cg, Bs + id * 8);
        }
        __syncthreads();
#pragma unroll
        for (int c = 0; c < 2; ++c) {
            bf16x8 af[2], bfv[4];
#pragma unroll
            for (int i = 0; i < 2; ++i)
                af[i] = *reinterpret_cast<const bf16x8*>(
                    &As[(wm * 32 + i * 16 + l15) * 64 + ((c * 32 + l4 * 8) ^ swzr)]);
#pragma unroll
            for (int j = 0; j < 4; ++j)
                bfv[j] = *reinterpret_cast<const bf16x8*>(
                    &Bs[(wn * 64 + j * 16 + l15) * 64 + ((c * 32 + l4 * 8) ^ swzr)]);
#pragma unroll
            for (int i = 0; i < 2; ++i)
#pragma unroll
                for (int j = 0; j < 4; ++j)
                    acc[i][j] = __builtin_amdgcn_mfma_f32_16x16x32_bf16(
                        af[i], bfv[j], acc[i][j], 0, 0, 0);
        }
    }
    float* Cz = C ? C + (size_t)z * sC : nullptr;
    unsigned short* Cbz = Cbf ? Cbf + (size_t)z * sC : nullptr;
    if (epi == 3) {
        // exp + bf16 store + per-row denominator accumulation
#pragma unroll
        for (int i = 0; i < 2; ++i)
#pragma unroll
            for (int r = 0; r < 4; ++r) {
                size_t row = bm + wm * 32 + i * 16 + l4 * 4 + r;
                float s = 0.f;
#pragma unroll
                for (int j = 0; j < 4; ++j) {
                    size_t col = bn + wn * 64 + j * 16 + l15;
                    float e = __expf(acc[i][j][r]);
                    s += e;
                    Cbz[row * (size_t)ldc + col] = f2bf(e);
                }
                s += __shfl_xor(s, 1); s += __shfl_xor(s, 2);
                s += __shfl_xor(s, 4); s += __shfl_xor(s, 8);
                if (l15 == 0) atomicAdd(denv + (size_t)z * MLM + row, s);
            }
        return;
    }
#pragma unroll
    for (int i = 0; i < 2; ++i)
#pragma unroll
        for (int j = 0; j < 4; ++j)
#pragma unroll
            for (int r = 0; r < 4; ++r) {
                size_t row = bm + wm * 32 + i * 16 + l4 * 4 + r;
                size_t col = bn + wn * 64 + j * 16 + l15;
                float v = acc[i][j][r];
                if (bias) v += bias[col];
                if (epi == 2) {
                    float xl = alphav[row] * v;
                    float w = 1.f / (1.f + __expf(xl));
                    float sq = w * w;
                    v = xl * 2.f * sq + 2.f * addsrc[row * (size_t)ldc + col] * (1.f - sq);
                    Cz[row * (size_t)ldc + col] = v;
                } else {
                    if (addsrc) v += addsrc[row * (size_t)ldc + col];
                    if (epi == 1) v = __expf(v);
                    if (Cz)  Cz[row * (size_t)ldc + col] = v;
                    if (Cbz) Cbz[row * (size_t)ldc + col] = f2bf(v);
                }
            }
}

// ===== bf16 NT GEMM for pinv, whole-K staging (K=256): C = beta*(A@B)+alpha*A =====
// A row-major [Mx256]; B^T row-major [Nx256]. 64x64 tile, 4 waves 2x2, wave 32x32.
// All 16 global_load_lds issued up front; ONE barrier; 5-bit XOR swizzle.
__global__ __launch_bounds__(256) void bmm_h(
    const unsigned short* __restrict__ Ah, const unsigned short* __restrict__ Bh,
    unsigned short* __restrict__ Crh, unsigned short* __restrict__ Cth,
    int M, int N, int ntn, float alpha, float beta)
{
    __shared__ __align__(16) unsigned short LA[64 * 256];   // 32 KB
    __shared__ __align__(16) unsigned short LB[64 * 256];   // 32 KB
    const int tid = threadIdx.x;
    const int wave = tid >> 6, lane = tid & 63;
    const int l15 = lane & 15, l4 = lane >> 4;
    const int wm = wave >> 1, wn = wave & 1;
    const int b = blockIdx.y;
    const int tm = blockIdx.x / ntn, tn = blockIdx.x % ntn;
    const unsigned short* Ahb = Ah + (size_t)b * M * 256;
    const unsigned short* Bhb = Bh + (size_t)b * N * 256;
#pragma unroll
    for (int s = 0; s < 8; ++s) {              // A: 64 rows x 32 groups of 8
        int id = s * 256 + tid;
        int row = id >> 5, gp = id & 31;
        int src = (gp ^ (row & 31)) << 3;
        gload_lds16(Ahb + (size_t)(tm * 64 + row) * 256 + src, LA + id * 8);
    }
#pragma unroll
    for (int s = 0; s < 8; ++s) {              // B
        int id = s * 256 + tid;
        int row = id >> 5, gp = id & 31;
        int src = (gp ^ (row & 31)) << 3;
        gload_lds16(Bhb + (size_t)(tn * 64 + row) * 256 + src, LB + id * 8);
    }
    __syncthreads();
    f32x4 acc[2][2] = {};
#pragma unroll
    for (int k0 = 0; k0 < 8; ++k0) {
        bf16x8 ah[2], bh[2];
#pragma unroll
        for (int i = 0; i < 2; ++i) {
            int row = wm * 32 + i * 16 + l15;
            int gi = k0 * 4 + l4;
            ah[i] = *reinterpret_cast<const bf16x8*>(
                &LA[row * 256 + ((gi ^ (row & 31)) << 3)]);
        }
#pragma unroll
        for (int j = 0; j < 2; ++j) {
            int row = wn * 32 + j * 16 + l15;
            int gi = k0 * 4 + l4;
            bh[j] = *reinterpret_cast<const bf16x8*>(
                &LB[row * 256 + ((gi ^ (row & 31)) << 3)]);
        }
#pragma unroll
        for (int i = 0; i < 2; ++i)
#pragma unroll
            for (int j = 0; j < 2; ++j)
                acc[i][j] = __builtin_amdgcn_mfma_f32_16x16x32_bf16(ah[i], bh[j], acc[i][j], 0, 0, 0);
    }
    unsigned short* Crhb = Crh ? Crh + (size_t)b * M * N : nullptr;
    unsigned short* Cthb = Cth ? Cth + (size_t)b * M * N : nullptr;
#pragma unroll
    for (int i = 0; i < 2; ++i)
#pragma unroll
        for (int j = 0; j < 2; ++j)
#pragma unroll
            for (int r = 0; r < 4; ++r) {
                int row = tm * 64 + wm * 32 + i * 16 + l4 * 4 + r;
                int col = tn * 64 + wn * 32 + j * 16 + l15;
                float v = beta * acc[i][j][r];
                if (alpha != 0.f)
                    v += alpha * bf2f(Ahb[(size_t)row * 256 + col]);   // square (M==K) only
                unsigned short hi = f2bf(v);
                if (Crhb) Crhb[(size_t)row * N + col] = hi;
                if (Cthb) Cthb[(size_t)col * M + row] = hi;
            }
}

// ===== pv3: partials[kc][h][i][d] = sum_{j in chunk} P[h,i,j]*vT[h,d,j] =====
__global__ __launch_bounds__(256) void pv3_mfma(
    const unsigned short* __restrict__ sc, const unsigned short* __restrict__ vT,
    float* __restrict__ part)
{
    __shared__ __align__(16) unsigned short As[64 * 64];
    __shared__ __align__(16) unsigned short Bs[64 * 64];
    const int tid = threadIdx.x;
    const int wave = tid >> 6, lane = tid & 63;
    const int l15 = lane & 15, l4 = lane >> 4;
    const int wm = wave >> 1, wn = wave & 1;
    const int it = blockIdx.x, kc = blockIdx.y, h = blockIdx.z;
    const unsigned short* Ap = sc + (size_t)h * MLM * NSEQ + (size_t)(it * 64) * NSEQ + kc * 512;
    const unsigned short* Bp = vT + (size_t)h * DH * NSEQ + kc * 512;
    const int swzr = (l15 & 7) << 3;
    f32x4 acc[2][2] = {};
    for (int k0 = 0; k0 < 512; k0 += 64) {
        __syncthreads();
#pragma unroll
        for (int c2 = 0; c2 < 2; ++c2) {
            int id = c2 * 256 + tid;
            int row = id >> 3;
            int cg = ((id & 7) ^ (row & 7)) << 3;
            gload_lds16(Ap + (size_t)row * NSEQ + k0 + cg, As + id * 8);
        }
#pragma unroll
        for (int c2 = 0; c2 < 2; ++c2) {
            int id = c2 * 256 + tid;
            int row = id >> 3;
            int cg = ((id & 7) ^ (row & 7)) << 3;
            gload_lds16(Bp + (size_t)row * NSEQ + k0 + cg, Bs + id * 8);
        }
        __syncthreads();
#pragma unroll
        for (int ks = 0; ks < 2; ++ks) {
            bf16x8 af[2], bfv[2];
#pragma unroll
            for (int i = 0; i < 2; ++i)
                af[i] = *reinterpret_cast<const bf16x8*>(
                    &As[(wm * 32 + i * 16 + l15) * 64 + ((ks * 32 + l4 * 8) ^ swzr)]);
#pragma unroll
            for (int j = 0; j < 2; ++j)
                bfv[j] = *reinterpret_cast<const bf16x8*>(
                    &Bs[(wn * 32 + j * 16 + l15) * 64 + ((ks * 32 + l4 * 8) ^ swzr)]);
#pragma unroll
            for (int i = 0; i < 2; ++i)
#pragma unroll
                for (int j = 0; j < 2; ++j)
                    acc[i][j] = __builtin_amdgcn_mfma_f32_16x16x32_bf16(af[i], bfv[j], acc[i][j], 0, 0, 0);
        }
    }
    float* Cp = part + ((size_t)(kc * 8 + h) * MLM + it * 64) * DH;
#pragma unroll
    for (int i = 0; i < 2; ++i)
#pragma unroll
        for (int j = 0; j < 2; ++j)
#pragma unroll
            for (int r = 0; r < 4; ++r)
                Cp[(wm * 32 + i * 16 + l4 * 4 + r) * DH + wn * 32 + j * 16 + l15] = acc[i][j][r];
}

// ===== fused a1 (round-10 proven): QK + exp-softmax + PV + conv -> bf16 attn =====
// LDS: A(8KB) overlapped by P(32KB) overlapped by att(16KB)+vbuf(12KB); kls/bbT from L2.
__global__ __launch_bounds__(256) void a1_fused(
    const unsigned short* __restrict__ qkvbf,
    const unsigned short* __restrict__ kls,     // [h][256][64] (k_l * 0.125)
    const unsigned short* __restrict__ bbT,     // [h][64][256]
    const float* __restrict__ kern,
    unsigned short* __restrict__ attnbf)
{
    __shared__ __align__(16) unsigned short lds[16384];  // 32 KB
    __shared__ float den[2][64];
    __shared__ float kc_s[KCONV];
    const int tid = threadIdx.x;
    const int wave = tid >> 6, lane = tid & 63;
    const int l15 = lane & 15, l4 = lane >> 4;
    const int wm = wave >> 1, wn = wave & 1;
    const int n0 = blockIdx.x * 64;
    const int h = blockIdx.y;
    const int swzr = (l15 & 7) << 3;

    if (tid < KCONV) kc_s[tid] = kern[h * KCONV + tid];
    // stage A (q rows 64x64) only; kls fragments come straight from L2
#pragma unroll
    for (int c2 = 0; c2 < 2; ++c2) {
        int id = c2 * 256 + tid;
        int row = id >> 3, cg = ((id & 7) ^ (row & 7)) << 3;
        gload_lds16(qkvbf + (size_t)(n0 + row) * QKV_LD + h * DH + cg, lds + id * 8);
    }
    __syncthreads();
    // QK: S = q . kls^T  (64 x 256), wave tile 32 x 128
    const unsigned short* klsh = kls + (size_t)h * (MLM * DH);
    f32x4 acc[2][8] = {};
#pragma unroll
    for (int c = 0; c < 2; ++c) {
        bf16x8 af[2], bv[8];
#pragma unroll
        for (int i = 0; i < 2; ++i) {
            int row = wm * 32 + i * 16 + l15;
            af[i] = *reinterpret_cast<const bf16x8*>(&lds[row * 64 + ((c * 32 + l4 * 8) ^ swzr)]);
        }
#pragma unroll
        for (int j = 0; j < 8; ++j) {
            int brow = wn * 128 + j * 16 + l15;
            bv[j] = *reinterpret_cast<const bf16x8*>(&klsh[brow * 64 + c * 32 + l4 * 8]);
        }
#pragma unroll
        for (int i = 0; i < 2; ++i)
#pragma unroll
            for (int j = 0; j < 8; ++j)
                acc[i][j] = __builtin_amdgcn_mfma_f32_16x16x32_bf16(af[i], bv[j], acc[i][j], 0, 0, 0);
    }
    __syncthreads();   // all A reads complete -> P may overlay
    // exp (scores tiny: no max), row sums, write P bf16 swizzled at lds[0]
    float rs[2][4] = {};
#pragma unroll
    for (int i = 0; i < 2; ++i)
#pragma unroll
        for (int j = 0; j < 8; ++j)
#pragma unroll
            for (int r = 0; r < 4; ++r) {
                float e = __expf(acc[i][j][r]);
                rs[i][r] += e;
                int row = wm * 32 + i * 16 + l4 * 4 + r;
                int col = wn * 128 + j * 16 + l15;
                lds[row * 256 + (col ^ ((row & 7) << 3))] = f2bf(e);
            }
#pragma unroll
    for (int i = 0; i < 2; ++i)
#pragma unroll
        for (int r = 0; r < 4; ++r) {
            float s = rs[i][r];
            s += __shfl_xor(s, 1); s += __shfl_xor(s, 2);
            s += __shfl_xor(s, 4); s += __shfl_xor(s, 8);
            if (l15 == 0) den[wn][wm * 32 + i * 16 + l4 * 4 + r] = s;
        }
    __syncthreads();
    // PV: out = P @ bb  (64 x 64), wave tile 32 x 32; B frags from L2
    f32x4 acc2[2][2] = {};
    const unsigned short* bbh = bbT + (size_t)h * DH * MLM;
#pragma unroll
    for (int k0 = 0; k0 < 256; k0 += 32) {
        bf16x8 af2[2], bv2[2];
#pragma unroll
        for (int i = 0; i < 2; ++i) {
            int row = wm * 32 + i * 16 + l15;
            af2[i] = *reinterpret_cast<const bf16x8*>(
                &lds[row * 256 + ((k0 + l4 * 8) ^ ((row & 7) << 3))]);
        }
#pragma unroll
        for (int j = 0; j < 2; ++j) {
            int d = wn * 32 + j * 16 + l15;
            bv2[j] = *reinterpret_cast<const bf16x8*>(&bbh[d * MLM + k0 + l4 * 8]);
        }
#pragma unroll
        for (int i = 0; i < 2; ++i)
#pragma unroll
            for (int j = 0; j < 2; ++j)
                acc2[i][j] = __builtin_amdgcn_mfma_f32_16x16x32_bf16(af2[i], bv2[j], acc2[i][j], 0, 0, 0);
    }
    __syncthreads();   // P reads done; reuse LDS
    // normalized PV -> LDS fp32 att[64][64] at lds[0]; v window 96x64 at lds[8192]
    float* att = reinterpret_cast<float*>(lds);              // 16 KB
    unsigned short* vbuf = &lds[8192];                       // 12 KB
#pragma unroll
    for (int i = 0; i < 2; ++i)
#pragma unroll
        for (int r = 0; r < 4; ++r) {
            int row = wm * 32 + i * 16 + l4 * 4 + r;
            float inv = 1.f / (den[0][row] + den[1][row]);
#pragma unroll
            for (int j = 0; j < 2; ++j)
                att[row * 64 + wn * 32 + j * 16 + l15] = acc2[i][j][r] * inv;
        }
#pragma unroll
    for (int s = 0; s < 6; ++s) {
        int id = s * 256 + tid;
        int r = id >> 4, c4 = (id & 15) * 4;
        int n = n0 - 16 + r;
        ushort4 u = {0, 0, 0, 0};
        if (n >= 0 && n < NSEQ)
            u = *reinterpret_cast<const ushort4*>(qkvbf + (size_t)n * QKV_LD + 1024 + h * 64 + c4);
        *reinterpret_cast<ushort4*>(vbuf + r * 64 + c4) = u;
    }
    __syncthreads();
    // conv: each thread owns 16 rows of one column
    const int col = tid & 63, rowg = tid >> 6;
    float vwin[48];
#pragma unroll
    for (int t = 0; t < 48; ++t) vwin[t] = bf2f(vbuf[(rowg * 16 + t) * 64 + col]);
#pragma unroll
    for (int rr = 0; rr < 16; ++rr) {
        float cv = 0.f;
#pragma unroll
        for (int t = 0; t < KCONV; ++t) cv += kc_s[t] * vwin[rr + t];
        int row = rowg * 16 + rr;
        attnbf[(size_t)(n0 + row) * INNER + h * DH + col] = f2bf(att[row * 64 + col] + cv);
    }
}

// ------------- landmark means from bf16 qkv (+ bf16 copies) -------------
__global__ __launch_bounds__(64) void landmark2_k(
    const unsigned short* __restrict__ qkvbf, float* __restrict__ q_l, float* __restrict__ k_l,
    unsigned short* __restrict__ ql_bf, unsigned short* __restrict__ kls_bf)
{
    int m = blockIdx.x, h = blockIdx.y, d = threadIdx.x;
    float sq = 0.f, sk = 0.f;
    for (int i = 0; i < LSUB; ++i) {
        size_t n = (size_t)m * LSUB + i;
        sq += bf2f(qkvbf[n * QKV_LD + h * DH + d]);
        sk += bf2f(qkvbf[n * QKV_LD + 512 + h * DH + d]);
    }
    float qv = sq * (0.125f / (float)LSUB);
    float kv = sk * (1.f / (float)LSUB);
    size_t o = ((size_t)h * MLM + m) * DH + d;
    q_l[o] = qv; k_l[o] = kv;
    ql_bf[o] = f2bf(qv);
    kls_bf[o] = f2bf(kv * 0.125f);
}

// ------------- v transpose: vT[h][d][n] = qkv_bf[n][1024+h*64+d] -------------
__global__ __launch_bounds__(256) void vt_k(
    const unsigned short* __restrict__ qkvbf, unsigned short* __restrict__ vT)
{
    __shared__ unsigned short tile[128][72];
    const int t = threadIdx.x;
    const int n0 = blockIdx.x * 128;
    const int h = blockIdx.y;
#pragma unroll
    for (int s = 0; s < 4; ++s) {
        int cid = s * 256 + t;
        int row = cid >> 3, ch = (cid & 7) * 8;
        uint4 v = *reinterpret_cast<const uint4*>(
            qkvbf + (size_t)(n0 + row) * QKV_LD + 1024 + h * 64 + ch);
        *reinterpret_cast<uint4*>(&tile[row][ch]) = v;
    }
    __syncthreads();
#pragma unroll
    for (int s = 0; s < 4; ++s) {
        int cid = s * 256 + t;
        int d = cid >> 4, nch = (cid & 15) * 8;
        unsigned short o[8];
#pragma unroll
        for (int i = 0; i < 8; ++i) o[i] = tile[nch + i][d];
        *reinterpret_cast<uint4*>(vT + (size_t)h * DH * NSEQ + (size_t)d * NSEQ + n0 + nch) =
            *reinterpret_cast<uint4*>(o);
    }
}

// ------------- a2 = softmax(q_l @ k_l^T) rows -------------
__global__ __launch_bounds__(256) void a2_k(
    const float* __restrict__ q_l, const float* __restrict__ k_l, float* __restrict__ a2)
{
    int i = blockIdx.x, h = blockIdx.y, t = threadIdx.x;
    __shared__ float ql[64];
    __shared__ float red[256];
    if (t < 64) ql[t] = q_l[((size_t)h * MLM + i) * DH + t];
    __syncthreads();
    const float* kr = k_l + ((size_t)h * MLM + t) * DH;
    float s = 0.f;
#pragma unroll
    for (int d = 0; d < 64; d += 4) {
        float4 kv = *reinterpret_cast<const float4*>(kr + d);
        s += kv.x * ql[d] + kv.y * ql[d + 1] + kv.z * ql[d + 2] + kv.w * ql[d + 3];
    }
    red[t] = s; __syncthreads();
    for (int off = 128; off > 0; off >>= 1) { if (t < off) red[t] = fmaxf(red[t], red[t + off]); __syncthreads(); }
    float m = red[0]; __syncthreads();
    float e = __expf(s - m);
    red[t] = e; __syncthreads();
    for (int off = 128; off > 0; off >>= 1) { if (t < off) red[t] += red[t + off]; __syncthreads(); }
    a2[(((size_t)h * MLM + i) * MLM) + t] = e / red[0];
}

// ------------- global max of row/col abs-sums of a2 -------------
__global__ __launch_bounds__(256) void absmax_k(
    const float* __restrict__ a2, unsigned int* __restrict__ scal)
{
    int b = blockIdx.x, t = threadIdx.x;
    __shared__ float red[256];
    float sum = 0.f;
    if (b < 8) {
        const float* r = a2 + ((size_t)b * MLM + t) * MLM;
        for (int j = 0; j < MLM; ++j) sum += fabsf(r[j]);
    } else {
        int h = b - 8;
        for (int i = 0; i < MLM; ++i) sum += fabsf(a2[((size_t)h * MLM + i) * MLM + t]);
    }
    red[t] = sum; __syncthreads();
    for (int off = 128; off > 0; off >>= 1) { if (t < off) red[t] = fmaxf(red[t], red[t + off]); __syncthreads(); }
    if (t == 0) atomicMax(scal + (b < 8 ? 0 : 1), __float_as_uint(red[0]));
}

// ------------- zinit2: a2 + z0 (row & T) to bf16 -------------
__global__ __launch_bounds__(256) void zinit2_k(
    const float* __restrict__ a2, const unsigned int* __restrict__ scal,
    unsigned short* __restrict__ a2h,
    unsigned short* __restrict__ zrh, unsigned short* __restrict__ zth)
{
    int idx = blockIdx.x * 256 + threadIdx.x;
    float inv = 1.f / (__uint_as_float(scal[0]) * __uint_as_float(scal[1]));
    int h = idx >> 16, rem = idx & 65535, i = rem >> 8, j = rem & 255;
    float aij = a2[idx];
    a2h[idx] = f2bf(aij);
    zth[idx] = f2bf(aij * inv);                              // z0T[i][j] = a2[i][j]*inv
    zrh[idx] = f2bf(a2[((size_t)h << 16) + (j << 8) + i] * inv);  // z0row[i][j] = a2[j][i]*inv
}

// ------------- red3: sum partials, divide, write a3v^T bf16 -------------
__global__ __launch_bounds__(256) void red3_k(
    const float* __restrict__ part, const float* __restrict__ den3,
    unsigned short* __restrict__ a3vth)
{
    int o = blockIdx.x * 256 + threadIdx.x;   // [8][256][64]
    float s = 0.f;
#pragma unroll
    for (int kc = 0; kc < 16; ++kc) s += part[(size_t)kc * 131072 + o];
    s /= den3[o >> 6];
    int h = o >> 14, i = (o >> 6) & 255, d = o & 63;
    a3vth[(h << 14) + (d << 8) + i] = f2bf(s);
}

// ------------- sparse edge scores: 8 lanes/edge, 32 dims/lane -------------
__global__ __launch_bounds__(256) void edge2_k(
    const unsigned short* __restrict__ qke,
    const int* __restrict__ rows, const int* __restrict__ cols,
    const float* __restrict__ vals, float* __restrict__ A_raw)
{
    const int e = blockIdx.x * 32 + (threadIdx.x >> 3);
    const int g = threadIdx.x & 7;
    const int r = rows[e], c = cols[e];
    const unsigned short* qr = qke + (size_t)r * 512 + g * 32;
    const unsigned short* kr = qke + (size_t)c * 512 + 256 + g * 32;
    float s = 0.f;
#pragma unroll
    for (int u = 0; u < 4; ++u) {
        uint4 qa = *reinterpret_cast<const uint4*>(qr + u * 8);
        uint4 ka = *reinterpret_cast<const uint4*>(kr + u * 8);
        unsigned int qw[4] = {qa.x, qa.y, qa.z, qa.w};
        unsigned int kw[4] = {ka.x, ka.y, ka.z, ka.w};
#pragma unroll
        for (int q = 0; q < 4; ++q) {
            s += bf2f((unsigned short)(qw[q] & 0xFFFF)) * bf2f((unsigned short)(kw[q] & 0xFFFF));
            s += bf2f((unsigned short)(qw[q] >> 16)) * bf2f((unsigned short)(kw[q] >> 16));
        }
    }
    s += __shfl_xor(s, 1); s += __shfl_xor(s, 2); s += __shfl_xor(s, 4);
    if (g == 0) atomicAdd(&A_raw[r], s * vals[e] * 0.0625f);
}

// ------------- alpha = softmax(A_raw) -------------
__global__ __launch_bounds__(1024) void alpha_k(
    const float* __restrict__ A_raw, float* __restrict__ alpha)
{
    __shared__ float red[1024];
    int t = threadIdx.x;
    float m = -1e30f;
    for (int i = t; i < NSEQ; i += 1024) m = fmaxf(m, A_raw[i]);
    red[t] = m; __syncthreads();
    for (int off = 512; off > 0; off >>= 1) { if (t < off) red[t] = fmaxf(red[t], red[t + off]); __syncthreads(); }
    m = red[0]; __syncthreads();
    float s = 0.f;
    for (int i = t; i < NSEQ; i += 1024) s += __expf(A_raw[i] - m);
    red[t] = s; __syncthreads();
    for (int off = 512; off > 0; off >>= 1) { if (t < off) red[t] += red[t + off]; __syncthreads(); }
    float inv = 1.f / red[0];
    for (int i = t; i < NSEQ; i += 1024) alpha[i] = __expf(A_raw[i] - m) * inv;
}

extern "C" void kernel_launch(void* const* d_in, const int* in_sizes, int n_in,
                              void* d_out, int out_size, void* d_ws, size_t ws_size,
                              hipStream_t stream)
{
    const float* dense      = (const float*)d_in[0];
    const int*   adj_rows   = (const int*)d_in[1];
    const int*   adj_cols   = (const int*)d_in[2];
    const float* adj_vals   = (const float*)d_in[3];
    const float* wq         = (const float*)d_in[4];
    const float* wk         = (const float*)d_in[5];
    const float* w_qkv      = (const float*)d_in[6];
    const float* w_out      = (const float*)d_in[7];
    const float* b_out      = (const float*)d_in[8];
    const float* res_kernel = (const float*)d_in[9];
    const float* wv_w       = (const float*)d_in[10];
    const float* wv_b       = (const float*)d_in[11];
    const int E = in_sizes[1];

    float* ws  = (float*)d_ws;
    float* out = (float*)d_out;
    float* A_raw = out + (size_t)NSEQ * DDIM;

    unsigned short* qkv_bf   = (unsigned short*)(ws + OFF_QKVBF);
    unsigned short* vT       = (unsigned short*)(ws + OFF_VT);
    unsigned short* sc       = (unsigned short*)(ws + OFF_SC);
    unsigned short* attn_bf  = (unsigned short*)(ws + OFF_ATTNBF);
    unsigned short* qke_bf   = (unsigned short*)(ws + OFF_QKE);
    unsigned short* dense_bf = (unsigned short*)(ws + OFF_DENSEBF);
    unsigned short* wqkv_bf  = (unsigned short*)(ws + OFF_WQKVBF);
    unsigned short* wout_bf  = (unsigned short*)(ws + OFF_WOUTBF);
    unsigned short* wqkT_bf  = (unsigned short*)(ws + OFF_WQKT);
    unsigned short* wv_bf    = (unsigned short*)(ws + OFF_WVBF);
    unsigned short* ql_bf    = (unsigned short*)(ws + OFF_QLBF);
    unsigned short* kls_bf   = (unsigned short*)(ws + OFF_KLSBF);
    unsigned short* bbT_bf   = (unsigned short*)(ws + OFF_BBT);
    unsigned short* enc_bf   = (unsigned short*)(ws + OFF_ENCBF);

#define U16(off) ((unsigned short*)(ws + (off)))

    (void)hipMemsetAsync(A_raw, 0, NSEQ * sizeof(float), stream);
    (void)hipMemsetAsync(ws + OFF_SCAL, 0, 2 * sizeof(unsigned int), stream);
    (void)hipMemsetAsync(ws + OFF_DEN3, 0, HEADS * MLM * sizeof(float), stream);

    // ---- input conversions ----
    cvt_bf16_k<<<(NSEQ * DDIM) / 2048, 256, 0, stream>>>(dense, dense_bf);
    cvt_bf16_k<<<(1536 * DDIM) / 2048, 256, 0, stream>>>(w_qkv, wqkv_bf);

    // qkv = dense @ w_qkv^T  -> bf16
    gemm_mfma_ntb<<<dim3(NSEQ / 64, 1536 / 128, 1), 256, 0, stream>>>(
        dense_bf, DDIM, 0, wqkv_bf, DDIM, 0, nullptr, qkv_bf, QKV_LD, 0,
        DDIM, nullptr, nullptr, nullptr, nullptr, 0);

    landmark2_k<<<dim3(MLM, HEADS), 64, 0, stream>>>(
        qkv_bf, ws + OFF_QL, ws + OFF_KL, ql_bf, kls_bf);
    vt_k<<<dim3(NSEQ / 128, HEADS), 256, 0, stream>>>(qkv_bf, vT);

    // ---- a3 pipeline (exp-scores + fused den accumulation) ----
    gemm_mfma_ntb<<<dim3(MLM / 64, NSEQ / 128, HEADS), 256, 0, stream>>>(
        ql_bf, DH, (size_t)MLM * DH, qkv_bf + 512, QKV_LD, DH,
        nullptr, sc, NSEQ, (size_t)MLM * NSEQ, DH, nullptr, nullptr, nullptr,
        ws + OFF_DEN3, 3);
    pv3_mfma<<<dim3(4, 16, HEADS), 256, 0, stream>>>(sc, vT, ws + OFF_PART);
    red3_k<<<512, 256, 0, stream>>>(ws + OFF_PART, ws + OFF_DEN3, U16(A3VT_H));

    a2_k<<<dim3(MLM, HEADS), 256, 0, stream>>>(ws + OFF_QL, ws + OFF_KL, ws + A2F32);
    absmax_k<<<16, 256, 0, stream>>>(ws + A2F32, (unsigned int*)(ws + OFF_SCAL));
    zinit2_k<<<(HEADS * MLM * MLM) / 256, 256, 0, stream>>>(
        ws + A2F32, (const unsigned int*)(ws + OFF_SCAL),
        U16(A2R_H), U16(Z0R_H), U16(Z0T_H));

    // pinv iterations (bf16 MFMA, whole-K staging)
    for (int it = 0; it < 6; ++it) {
        size_t zr_h = (it & 1) ? Z1R_H : Z0R_H;
        size_t zt_h = (it & 1) ? Z1T_H : Z0T_H;
        size_t or_h = (it & 1) ? Z0R_H : Z1R_H;
        size_t ot_h = (it & 1) ? Z0T_H : Z1T_H;
        bmm_h<<<dim3(16, HEADS), 256, 0, stream>>>(
            U16(A2R_H), U16(zt_h), U16(PR_H), U16(PT_H), 256, 256, 4, 0.f, 1.f);
        bmm_h<<<dim3(16, HEADS), 256, 0, stream>>>(
            U16(PR_H), U16(PT_H), nullptr, U16(T1T_H), 256, 256, 4, 7.f, -1.f);
        bmm_h<<<dim3(16, HEADS), 256, 0, stream>>>(
            U16(PR_H), U16(T1T_H), nullptr, U16(T2T_H), 256, 256, 4, 15.f, -1.f);
        bmm_h<<<dim3(16, HEADS), 256, 0, stream>>>(
            U16(zr_h), U16(T2T_H), U16(or_h), U16(ot_h), 256, 256, 4, 3.25f, -0.25f);
    }
    // bbT = (z @ a3v)^T = NT(a3vT, z_row)   [64 x 256]
    bmm_h<<<dim3(4, HEADS), 256, 0, stream>>>(
        U16(A3VT_H), U16(Z0R_H), bbT_bf, nullptr, 64, 256, 4, 0.f, 1.f);

    // ---- fused a1 (QK + exp-softmax + PV + conv -> bf16 attn) ----
    a1_fused<<<dim3(NSEQ / 64, HEADS), 256, 0, stream>>>(
        qkv_bf, kls_bf, bbT_bf, res_kernel, attn_bf);

    // ---- late weights to bf16 (single merged launch) ----
    wcvt_k<<<1280, 256, 0, stream>>>(w_out, wout_bf, wv_w, wv_bf, wq, wk, wqkT_bf);

    // enc = attn @ w_out^T + b_out + dense  (fp32 + bf16)
    gemm_mfma_ntb<<<dim3(NSEQ / 64, DDIM / 128, 1), 256, 0, stream>>>(
        attn_bf, INNER, 0, wout_bf, INNER, 0, ws + OFF_ENC, enc_bf, DDIM, 0,
        INNER, b_out, dense, nullptr, nullptr, 0);

    // qke = enc @ [wq|wk] -> bf16
    gemm_mfma_ntb<<<dim3(NSEQ / 64, 512 / 128, 1), 256, 0, stream>>>(
        enc_bf, DDIM, 0, wqkT_bf, DDIM, 0, nullptr, qke_bf, 512, 0,
        DDIM, nullptr, nullptr, nullptr, nullptr, 0);

    edge2_k<<<E / 32, 256, 0, stream>>>(qke_bf, adj_rows, adj_cols, adj_vals, A_raw);
    alpha_k<<<1, 1024, 0, stream>>>(A_raw, ws + OFF_ALPHA);

    // out = gated_blend(alpha, dense @ wv^T + wv_b, enc)  -- fused final
    gemm_mfma_ntb<<<dim3(NSEQ / 64, DDIM / 128, 1), 256, 0, stream>>>(
        dense_bf, DDIM, 0, wv_bf, DDIM, 0, out, nullptr, DDIM, 0,
        DDIM, wv_b, ws + OFF_ENC, ws + OFF_ALPHA, nullptr, 2);
}